// Round 1
// baseline (3183.302 us; speedup 1.0000x reference)
//
#include <hip/hip_runtime.h>
#include <hip/hip_bf16.h>
#include <cmath>

// Problem constants (fixed by reference)
constexpr int Bb = 2;
constexpr int Ls = 2048;
constexpr int Dd = 1024;
constexpr int Hh = 16;
constexpr int DHh = 64;
constexpr int Rr = 32;
constexpr int BL = Bb * Ls;          // 4096
constexpr float LORA_SCALE = 2.0f;   // 64/32
constexpr float LN_EPS = 1e-5f;
constexpr float ATTN_SCALE = 0.125f; // 1/sqrt(64)

// ---------------- block-wide sum over 256 threads ----------------
__device__ __forceinline__ float block_sum_256(float v, float* red) {
#pragma unroll
    for (int o = 32; o > 0; o >>= 1) v += __shfl_down(v, o, 64);
    const int lane = threadIdx.x & 63;
    const int wid = threadIdx.x >> 6;
    if (lane == 0) red[wid] = v;
    __syncthreads();
    float s = red[0] + red[1] + red[2] + red[3];
    __syncthreads();
    return s;
}

// ---------------- 1. LayerNorm(x) -> h ----------------
__global__ __launch_bounds__(256) void ln_x_kernel(const float* __restrict__ x,
                                                   const float* __restrict__ w,
                                                   const float* __restrict__ b,
                                                   float* __restrict__ h) {
    const int row = blockIdx.x;
    const int tid = threadIdx.x;
    __shared__ float red[4];
    float4 xv = *(const float4*)(x + (size_t)row * Dd + tid * 4);
    float v[4] = {xv.x, xv.y, xv.z, xv.w};
    float s = v[0] + v[1] + v[2] + v[3];
    float mean = block_sum_256(s, red) * (1.0f / Dd);
    float sq = 0.f;
#pragma unroll
    for (int j = 0; j < 4; ++j) {
        v[j] -= mean;
        sq += v[j] * v[j];
    }
    float var = block_sum_256(sq, red) * (1.0f / Dd);
    float rs = rsqrtf(var + LN_EPS);
#pragma unroll
    for (int j = 0; j < 4; ++j) {
        int d = tid * 4 + j;
        h[(size_t)row * Dd + d] = v[j] * rs * w[d] + b[d];
    }
}

// ---------------- 2. generic GEMM: C[M,N] = A[M,K] * B[N,K]^T ----------------
__global__ __launch_bounds__(256) void gemm_abt(const float* __restrict__ A,
                                                const float* __restrict__ B,
                                                float* __restrict__ C,
                                                int M, int N, int K) {
    __shared__ float As[16][64];
    __shared__ float Bs[16][64];
    const int tx = threadIdx.x % 16;
    const int ty = threadIdx.x / 16;
    const int m0 = blockIdx.y * 64;
    const int n0 = blockIdx.x * 64;
    const int am = threadIdx.x >> 2;         // 0..63
    const int ak = (threadIdx.x & 3) * 4;    // 0,4,8,12
    float acc[4][4] = {};
    for (int k0 = 0; k0 < K; k0 += 16) {
        float4 av = *(const float4*)(A + (size_t)(m0 + am) * K + k0 + ak);
        float4 bv = *(const float4*)(B + (size_t)(n0 + am) * K + k0 + ak);
        As[ak + 0][am] = av.x; As[ak + 1][am] = av.y;
        As[ak + 2][am] = av.z; As[ak + 3][am] = av.w;
        Bs[ak + 0][am] = bv.x; Bs[ak + 1][am] = bv.y;
        Bs[ak + 2][am] = bv.z; Bs[ak + 3][am] = bv.w;
        __syncthreads();
#pragma unroll
        for (int kt = 0; kt < 16; ++kt) {
            float a[4], bb[4];
#pragma unroll
            for (int i = 0; i < 4; ++i) a[i] = As[kt][ty * 4 + i];
#pragma unroll
            for (int j = 0; j < 4; ++j) bb[j] = Bs[kt][tx * 4 + j];
#pragma unroll
            for (int i = 0; i < 4; ++i)
#pragma unroll
                for (int j = 0; j < 4; ++j) acc[i][j] += a[i] * bb[j];
        }
        __syncthreads();
    }
#pragma unroll
    for (int i = 0; i < 4; ++i)
#pragma unroll
        for (int j = 0; j < 4; ++j)
            C[(size_t)(m0 + ty * 4 + i) * N + n0 + tx * 4 + j] = acc[i][j];
}

// ---------------- 3. LoRA down-proj: qtmp/vtmp[row][r] = h_row . a[r] ----------------
__global__ __launch_bounds__(256) void lora_tmp_kernel(const float* __restrict__ h,
                                                       const float* __restrict__ qa,
                                                       const float* __restrict__ va,
                                                       float* __restrict__ qtmp,
                                                       float* __restrict__ vtmp) {
    const int row = blockIdx.x;
    const int tid = threadIdx.x;
    __shared__ float hr[Dd];
    __shared__ float sred[256];
    float4 hv = *(const float4*)(h + (size_t)row * Dd + tid * 4);
    *(float4*)(hr + tid * 4) = hv;
    __syncthreads();
    const int out_id = tid >> 2;   // 0..63 (32 q + 32 v)
    const int part = tid & 3;
    const float* a = (out_id < Rr) ? (qa + (size_t)out_id * Dd)
                                   : (va + (size_t)(out_id - Rr) * Dd);
    float partial = 0.f;
    const int dbase = part * 256;
    for (int d = 0; d < 256; d += 4) {
        float4 av = *(const float4*)(a + dbase + d);
        partial += hr[dbase + d] * av.x + hr[dbase + d + 1] * av.y +
                   hr[dbase + d + 2] * av.z + hr[dbase + d + 3] * av.w;
    }
    sred[tid] = partial;
    __syncthreads();
    if (part == 0) {
        float t = sred[tid] + sred[tid + 1] + sred[tid + 2] + sred[tid + 3];
        if (out_id < Rr) qtmp[(size_t)row * Rr + out_id] = t;
        else vtmp[(size_t)row * Rr + (out_id - Rr)] = t;
    }
}

// ---------------- 4a. Q path: +lora, LN, RoPE, transpose to [B,H,L,DH] ----------------
__global__ __launch_bounds__(256) void q_final_kernel(const float* __restrict__ qkv,
                                                      const float* __restrict__ qtmp,
                                                      const float* __restrict__ qb,
                                                      const float* __restrict__ qlnw,
                                                      float* __restrict__ qt) {
    const int row = blockIdx.x;
    const int b = row >> 11;
    const int l = row & (Ls - 1);
    const int tid = threadIdx.x;
    __shared__ float tl[Rr];
    __shared__ float red[4];
    __shared__ float yrow[Dd];
    if (tid < Rr) tl[tid] = qtmp[(size_t)row * Rr + tid];
    __syncthreads();
    float4 qv = *(const float4*)(qkv + (size_t)row * (3 * Dd) + tid * 4);
    float v[4] = {qv.x, qv.y, qv.z, qv.w};
#pragma unroll
    for (int j = 0; j < 4; ++j) {
        int d = tid * 4 + j;
        float s = 0.f;
        for (int r = 0; r < Rr; r += 4) {
            float4 bv = *(const float4*)(qb + (size_t)d * Rr + r);
            s += tl[r] * bv.x + tl[r + 1] * bv.y + tl[r + 2] * bv.z + tl[r + 3] * bv.w;
        }
        v[j] += LORA_SCALE * s;
    }
    float s = v[0] + v[1] + v[2] + v[3];
    float mean = block_sum_256(s, red) * (1.0f / Dd);
    float sq = 0.f;
#pragma unroll
    for (int j = 0; j < 4; ++j) {
        v[j] -= mean;
        sq += v[j] * v[j];
    }
    float var = block_sum_256(sq, red) * (1.0f / Dd);
    float rs = rsqrtf(var + LN_EPS);
#pragma unroll
    for (int j = 0; j < 4; ++j) {
        int d = tid * 4 + j;
        yrow[d] = v[j] * rs * qlnw[d];
    }
    __syncthreads();
#pragma unroll
    for (int j = 0; j < 4; ++j) {
        int d = tid * 4 + j;
        int hh = d >> 6;
        int dh = d & 63;
        int i = dh & 31;
        float invf = powf(10000.0f, -(float)i * (1.0f / 32.0f));
        float ang = (float)l * invf;
        float sn, cs;
        sincosf(ang, &sn, &cs);
        float rot = (dh < 32) ? -yrow[d + 32] : yrow[d - 32];
        qt[(((size_t)(b * Hh + hh)) * Ls + l) * DHh + dh] = yrow[d] * cs + rot * sn;
    }
}

// ---------------- 4b. K path: LN, RoPE, transpose ----------------
__global__ __launch_bounds__(256) void k_final_kernel(const float* __restrict__ qkv,
                                                      const float* __restrict__ klnw,
                                                      float* __restrict__ kt) {
    const int row = blockIdx.x;
    const int b = row >> 11;
    const int l = row & (Ls - 1);
    const int tid = threadIdx.x;
    __shared__ float red[4];
    __shared__ float yrow[Dd];
    float4 kv = *(const float4*)(qkv + (size_t)row * (3 * Dd) + Dd + tid * 4);
    float v[4] = {kv.x, kv.y, kv.z, kv.w};
    float s = v[0] + v[1] + v[2] + v[3];
    float mean = block_sum_256(s, red) * (1.0f / Dd);
    float sq = 0.f;
#pragma unroll
    for (int j = 0; j < 4; ++j) {
        v[j] -= mean;
        sq += v[j] * v[j];
    }
    float var = block_sum_256(sq, red) * (1.0f / Dd);
    float rs = rsqrtf(var + LN_EPS);
#pragma unroll
    for (int j = 0; j < 4; ++j) {
        int d = tid * 4 + j;
        yrow[d] = v[j] * rs * klnw[d];
    }
    __syncthreads();
#pragma unroll
    for (int j = 0; j < 4; ++j) {
        int d = tid * 4 + j;
        int hh = d >> 6;
        int dh = d & 63;
        int i = dh & 31;
        float invf = powf(10000.0f, -(float)i * (1.0f / 32.0f));
        float ang = (float)l * invf;
        float sn, cs;
        sincosf(ang, &sn, &cs);
        float rot = (dh < 32) ? -yrow[d + 32] : yrow[d - 32];
        kt[(((size_t)(b * Hh + hh)) * Ls + l) * DHh + dh] = yrow[d] * cs + rot * sn;
    }
}

// ---------------- 4c. V path: +lora, transpose ----------------
__global__ __launch_bounds__(256) void v_final_kernel(const float* __restrict__ qkv,
                                                      const float* __restrict__ vtmp,
                                                      const float* __restrict__ vb,
                                                      float* __restrict__ vt) {
    const int row = blockIdx.x;
    const int b = row >> 11;
    const int l = row & (Ls - 1);
    const int tid = threadIdx.x;
    __shared__ float tl[Rr];
    if (tid < Rr) tl[tid] = vtmp[(size_t)row * Rr + tid];
    __syncthreads();
    float4 vv = *(const float4*)(qkv + (size_t)row * (3 * Dd) + 2 * Dd + tid * 4);
    float v[4] = {vv.x, vv.y, vv.z, vv.w};
#pragma unroll
    for (int j = 0; j < 4; ++j) {
        int d = tid * 4 + j;
        float s = 0.f;
        for (int r = 0; r < Rr; r += 4) {
            float4 bv = *(const float4*)(vb + (size_t)d * Rr + r);
            s += tl[r] * bv.x + tl[r + 1] * bv.y + tl[r + 2] * bv.z + tl[r + 3] * bv.w;
        }
        v[j] += LORA_SCALE * s;
        int hh = d >> 6;
        int dh = d & 63;
        vt[(((size_t)(b * Hh + hh)) * Ls + l) * DHh + dh] = v[j];
    }
}

// ---------------- 5. masked flash attention ----------------
// grid: (L/16, H, B), block 256. Each wave (qg) owns 4 query rows; lane = key j
// for scores, lane = dh for PV.
__global__ __launch_bounds__(256) void attn_kernel(const float* __restrict__ qt,
                                                   const float* __restrict__ kt,
                                                   const float* __restrict__ vt,
                                                   const int* __restrict__ seq_id,
                                                   float* __restrict__ ctx) {
    constexpr int TQ = 16, TK = 64;
    const int q0 = blockIdx.x * TQ;
    const int h = blockIdx.y;
    const int b = blockIdx.z;
    const size_t base = ((size_t)(b * Hh + h)) * Ls * DHh;
    __shared__ float qs[TQ][DHh + 1];
    __shared__ float ks[TK][DHh + 1];
    __shared__ float vs[TK][DHh + 1];
    __shared__ float ps[TQ][TK + 1];
    __shared__ float mrow[TQ], lrow[TQ], arow[TQ];
    __shared__ int sq[TQ];
    __shared__ int sk[TK];
    const int tid = threadIdx.x;
    {
        int fl = tid * 4;
        int r = fl >> 6, c = fl & 63;
        float4 v = *(const float4*)(qt + base + (size_t)(q0) * DHh + fl);
        qs[r][c] = v.x; qs[r][c + 1] = v.y; qs[r][c + 2] = v.z; qs[r][c + 3] = v.w;
    }
    if (tid < TQ) {
        sq[tid] = seq_id[(size_t)b * Ls + q0 + tid];
        mrow[tid] = -1e30f;
        lrow[tid] = 0.f;
    }
    const int lane = tid & 63;
    const int qg = tid >> 6;
    float acc[4] = {0.f, 0.f, 0.f, 0.f};
    for (int k0 = 0; k0 < Ls; k0 += TK) {
        __syncthreads();  // protect ks/vs/ps/sk from previous iteration readers
#pragma unroll
        for (int jj = 0; jj < 4; ++jj) {
            int fl = jj * 1024 + tid * 4;
            int r = fl >> 6, c = fl & 63;
            float4 kv = *(const float4*)(kt + base + (size_t)k0 * DHh + fl);
            ks[r][c] = kv.x; ks[r][c + 1] = kv.y; ks[r][c + 2] = kv.z; ks[r][c + 3] = kv.w;
            float4 vv = *(const float4*)(vt + base + (size_t)k0 * DHh + fl);
            vs[r][c] = vv.x; vs[r][c + 1] = vv.y; vs[r][c + 2] = vv.z; vs[r][c + 3] = vv.w;
        }
        if (tid < TK) sk[tid] = seq_id[(size_t)b * Ls + k0 + tid];
        __syncthreads();
        // scores: wave qg computes rows qi = qg*4..qg*4+3, lane = key index
        const int kj = lane;
#pragma unroll
        for (int ii = 0; ii < 4; ++ii) {
            int qi = qg * 4 + ii;
            float s = 0.f;
#pragma unroll
            for (int d2 = 0; d2 < DHh; ++d2) s += qs[qi][d2] * ks[kj][d2];
            s *= ATTN_SCALE;
            if (sq[qi] != sk[kj]) s = -3.0e38f;
            ps[qi][kj] = s;
        }
        __syncthreads();
        if (tid < TQ) {
            float m_old = mrow[tid];
            float mx = m_old;
            for (int j = 0; j < TK; ++j) mx = fmaxf(mx, ps[tid][j]);
            float alpha = expf(m_old - mx);
            float sum = 0.f;
            for (int j = 0; j < TK; ++j) {
                float p = expf(ps[tid][j] - mx);
                ps[tid][j] = p;
                sum += p;
            }
            lrow[tid] = lrow[tid] * alpha + sum;
            mrow[tid] = mx;
            arow[tid] = alpha;
        }
        __syncthreads();
        // PV: lane = dh, wave qg owns rows qg*4..+3
        const int dh = lane;
#pragma unroll
        for (int ii = 0; ii < 4; ++ii) {
            int qi = qg * 4 + ii;
            float a = acc[ii] * arow[qi];
            for (int j = 0; j < TK; ++j) a += ps[qi][j] * vs[j][dh];
            acc[ii] = a;
        }
    }
    __syncthreads();
    const int dh = lane;
#pragma unroll
    for (int ii = 0; ii < 4; ++ii) {
        int qi = qg * 4 + ii;
        ctx[((size_t)b * Ls + q0 + qi) * Dd + h * DHh + dh] = acc[ii] / lrow[qi];
    }
}

// ---------------- launcher ----------------
extern "C" void kernel_launch(void* const* d_in, const int* in_sizes, int n_in,
                              void* d_out, int out_size, void* d_ws, size_t ws_size,
                              hipStream_t stream) {
    const float* x = (const float*)d_in[0];
    const int* seq_id = (const int*)d_in[1];
    const float* ln_w = (const float*)d_in[2];
    const float* ln_b = (const float*)d_in[3];
    const float* w_qkv = (const float*)d_in[4];
    const float* q_lora_a = (const float*)d_in[5];
    const float* q_lora_b = (const float*)d_in[6];
    const float* v_lora_a = (const float*)d_in[7];
    const float* v_lora_b = (const float*)d_in[8];
    const float* q_ln_w = (const float*)d_in[9];
    const float* k_ln_w = (const float*)d_in[10];
    const float* w_out = (const float*)d_in[11];
    float* out = (float*)d_out;

    float* ws = (float*)d_ws;
    const size_t SZ = (size_t)BL * Dd;        // 4M elements
    float* h = ws;                            // [BL, D]
    float* qkv = ws + SZ;                     // [BL, 3D]
    float* q_t = ws + 4 * SZ;                 // [B, H, L, DH]
    float* k_t = ws + 5 * SZ;
    float* v_t = ws + 6 * SZ;
    float* qtmp = ws + 7 * SZ;                // [BL, R]
    float* vtmp = qtmp + (size_t)BL * Rr;
    float* ctx = h;                           // reuse: h dead after lora_tmp

    ln_x_kernel<<<BL, 256, 0, stream>>>(x, ln_w, ln_b, h);
    {
        dim3 g(3 * Dd / 64, BL / 64);
        gemm_abt<<<g, 256, 0, stream>>>(h, w_qkv, qkv, BL, 3 * Dd, Dd);
    }
    lora_tmp_kernel<<<BL, 256, 0, stream>>>(h, q_lora_a, v_lora_a, qtmp, vtmp);
    q_final_kernel<<<BL, 256, 0, stream>>>(qkv, qtmp, q_lora_b, q_ln_w, q_t);
    k_final_kernel<<<BL, 256, 0, stream>>>(qkv, k_ln_w, k_t);
    v_final_kernel<<<BL, 256, 0, stream>>>(qkv, vtmp, v_lora_b, v_t);
    {
        dim3 g(Ls / 16, Hh, Bb);
        attn_kernel<<<g, 256, 0, stream>>>(q_t, k_t, v_t, seq_id, ctx);
    }
    {
        dim3 g(Dd / 64, BL / 64);
        gemm_abt<<<g, 256, 0, stream>>>(ctx, w_out, out, BL, Dd, Dd);
    }
}

// Round 2
// 1004.738 us; speedup vs baseline: 3.1683x; 3.1683x over previous
//
#include <hip/hip_runtime.h>
#include <hip/hip_bf16.h>
#include <cmath>

// Problem constants (fixed by reference)
constexpr int Bb = 2;
constexpr int Ls = 2048;
constexpr int Dd = 1024;
constexpr int Hh = 16;
constexpr int DHh = 64;
constexpr int Rr = 32;
constexpr int BL = Bb * Ls;          // 4096
constexpr float LORA_SCALE = 2.0f;   // 64/32
constexpr float LN_EPS = 1e-5f;
constexpr float ATTN_SCALE = 0.125f; // 1/sqrt(64)
constexpr float LOG2E = 1.4426950408889634f;

typedef __attribute__((ext_vector_type(8))) short bf16x8;
typedef __attribute__((ext_vector_type(4))) float f32x4;

__device__ __forceinline__ unsigned short f2bf(float f) {
    __hip_bfloat16 b = __float2bfloat16(f);
    return *reinterpret_cast<unsigned short*>(&b);
}

// ---------------- block-wide sum over 256 threads ----------------
__device__ __forceinline__ float block_sum_256(float v, float* red) {
#pragma unroll
    for (int o = 32; o > 0; o >>= 1) v += __shfl_down(v, o, 64);
    const int lane = threadIdx.x & 63;
    const int wid = threadIdx.x >> 6;
    if (lane == 0) red[wid] = v;
    __syncthreads();
    float s = red[0] + red[1] + red[2] + red[3];
    __syncthreads();
    return s;
}

// ---------------- 1. LayerNorm(x) -> h ----------------
__global__ __launch_bounds__(256) void ln_x_kernel(const float* __restrict__ x,
                                                   const float* __restrict__ w,
                                                   const float* __restrict__ b,
                                                   float* __restrict__ h) {
    const int row = blockIdx.x;
    const int tid = threadIdx.x;
    __shared__ float red[4];
    float4 xv = *(const float4*)(x + (size_t)row * Dd + tid * 4);
    float v[4] = {xv.x, xv.y, xv.z, xv.w};
    float s = v[0] + v[1] + v[2] + v[3];
    float mean = block_sum_256(s, red) * (1.0f / Dd);
    float sq = 0.f;
#pragma unroll
    for (int j = 0; j < 4; ++j) {
        v[j] -= mean;
        sq += v[j] * v[j];
    }
    float var = block_sum_256(sq, red) * (1.0f / Dd);
    float rs = rsqrtf(var + LN_EPS);
#pragma unroll
    for (int j = 0; j < 4; ++j) {
        int d = tid * 4 + j;
        h[(size_t)row * Dd + d] = v[j] * rs * w[d] + b[d];
    }
}

// ---------------- 2. generic GEMM: C[M,N] = A[M,K] * B[N,K]^T ----------------
__global__ __launch_bounds__(256) void gemm_abt(const float* __restrict__ A,
                                                const float* __restrict__ B,
                                                float* __restrict__ C,
                                                int M, int N, int K) {
    __shared__ float As[16][64];
    __shared__ float Bs[16][64];
    const int tx = threadIdx.x % 16;
    const int ty = threadIdx.x / 16;
    const int m0 = blockIdx.y * 64;
    const int n0 = blockIdx.x * 64;
    const int am = threadIdx.x >> 2;         // 0..63
    const int ak = (threadIdx.x & 3) * 4;    // 0,4,8,12
    float acc[4][4] = {};
    for (int k0 = 0; k0 < K; k0 += 16) {
        float4 av = *(const float4*)(A + (size_t)(m0 + am) * K + k0 + ak);
        float4 bv = *(const float4*)(B + (size_t)(n0 + am) * K + k0 + ak);
        As[ak + 0][am] = av.x; As[ak + 1][am] = av.y;
        As[ak + 2][am] = av.z; As[ak + 3][am] = av.w;
        Bs[ak + 0][am] = bv.x; Bs[ak + 1][am] = bv.y;
        Bs[ak + 2][am] = bv.z; Bs[ak + 3][am] = bv.w;
        __syncthreads();
#pragma unroll
        for (int kt = 0; kt < 16; ++kt) {
            float a[4], bb[4];
#pragma unroll
            for (int i = 0; i < 4; ++i) a[i] = As[kt][ty * 4 + i];
#pragma unroll
            for (int j = 0; j < 4; ++j) bb[j] = Bs[kt][tx * 4 + j];
#pragma unroll
            for (int i = 0; i < 4; ++i)
#pragma unroll
                for (int j = 0; j < 4; ++j) acc[i][j] += a[i] * bb[j];
        }
        __syncthreads();
    }
#pragma unroll
    for (int i = 0; i < 4; ++i)
#pragma unroll
        for (int j = 0; j < 4; ++j)
            C[(size_t)(m0 + ty * 4 + i) * N + n0 + tx * 4 + j] = acc[i][j];
}

// ---------------- 3. LoRA down-proj ----------------
__global__ __launch_bounds__(256) void lora_tmp_kernel(const float* __restrict__ h,
                                                       const float* __restrict__ qa,
                                                       const float* __restrict__ va,
                                                       float* __restrict__ qtmp,
                                                       float* __restrict__ vtmp) {
    const int row = blockIdx.x;
    const int tid = threadIdx.x;
    __shared__ float hr[Dd];
    __shared__ float sred[256];
    float4 hv = *(const float4*)(h + (size_t)row * Dd + tid * 4);
    *(float4*)(hr + tid * 4) = hv;
    __syncthreads();
    const int out_id = tid >> 2;   // 0..63 (32 q + 32 v)
    const int part = tid & 3;
    const float* a = (out_id < Rr) ? (qa + (size_t)out_id * Dd)
                                   : (va + (size_t)(out_id - Rr) * Dd);
    float partial = 0.f;
    const int dbase = part * 256;
    for (int d = 0; d < 256; d += 4) {
        float4 av = *(const float4*)(a + dbase + d);
        partial += hr[dbase + d] * av.x + hr[dbase + d + 1] * av.y +
                   hr[dbase + d + 2] * av.z + hr[dbase + d + 3] * av.w;
    }
    sred[tid] = partial;
    __syncthreads();
    if (part == 0) {
        float t = sred[tid] + sred[tid + 1] + sred[tid + 2] + sred[tid + 3];
        if (out_id < Rr) qtmp[(size_t)row * Rr + out_id] = t;
        else vtmp[(size_t)row * Rr + (out_id - Rr)] = t;
    }
}

// ---------------- 4a. Q path: +lora, LN, RoPE, bf16 [B,H,L,DH] ----------------
__global__ __launch_bounds__(256) void q_final_kernel(const float* __restrict__ qkv,
                                                      const float* __restrict__ qtmp,
                                                      const float* __restrict__ qb,
                                                      const float* __restrict__ qlnw,
                                                      unsigned short* __restrict__ qt) {
    const int row = blockIdx.x;
    const int b = row >> 11;
    const int l = row & (Ls - 1);
    const int tid = threadIdx.x;
    __shared__ float tl[Rr];
    __shared__ float red[4];
    __shared__ float yrow[Dd];
    if (tid < Rr) tl[tid] = qtmp[(size_t)row * Rr + tid];
    __syncthreads();
    float4 qv = *(const float4*)(qkv + (size_t)row * (3 * Dd) + tid * 4);
    float v[4] = {qv.x, qv.y, qv.z, qv.w};
#pragma unroll
    for (int j = 0; j < 4; ++j) {
        int d = tid * 4 + j;
        float s = 0.f;
        for (int r = 0; r < Rr; r += 4) {
            float4 bv = *(const float4*)(qb + (size_t)d * Rr + r);
            s += tl[r] * bv.x + tl[r + 1] * bv.y + tl[r + 2] * bv.z + tl[r + 3] * bv.w;
        }
        v[j] += LORA_SCALE * s;
    }
    float s = v[0] + v[1] + v[2] + v[3];
    float mean = block_sum_256(s, red) * (1.0f / Dd);
    float sq = 0.f;
#pragma unroll
    for (int j = 0; j < 4; ++j) {
        v[j] -= mean;
        sq += v[j] * v[j];
    }
    float var = block_sum_256(sq, red) * (1.0f / Dd);
    float rs = rsqrtf(var + LN_EPS);
#pragma unroll
    for (int j = 0; j < 4; ++j) {
        int d = tid * 4 + j;
        yrow[d] = v[j] * rs * qlnw[d];
    }
    __syncthreads();
    const int d0 = tid * 4;
    const int hh = d0 >> 6;
    const int dh0 = d0 & 63;
    ushort4 pk;
    unsigned short* pp = (unsigned short*)&pk;
#pragma unroll
    for (int j = 0; j < 4; ++j) {
        int d = d0 + j;
        int dh = dh0 + j;
        int i = dh & 31;
        float invf = powf(10000.0f, -(float)i * (1.0f / 32.0f));
        float ang = (float)l * invf;
        float sn, cs;
        sincosf(ang, &sn, &cs);
        float rot = (dh < 32) ? -yrow[d + 32] : yrow[d - 32];
        pp[j] = f2bf(yrow[d] * cs + rot * sn);
    }
    *(ushort4*)(qt + (((size_t)(b * Hh + hh)) * Ls + l) * DHh + dh0) = pk;
}

// ---------------- 4b. K path: LN, RoPE, bf16 ----------------
__global__ __launch_bounds__(256) void k_final_kernel(const float* __restrict__ qkv,
                                                      const float* __restrict__ klnw,
                                                      unsigned short* __restrict__ kt) {
    const int row = blockIdx.x;
    const int b = row >> 11;
    const int l = row & (Ls - 1);
    const int tid = threadIdx.x;
    __shared__ float red[4];
    __shared__ float yrow[Dd];
    float4 kv = *(const float4*)(qkv + (size_t)row * (3 * Dd) + Dd + tid * 4);
    float v[4] = {kv.x, kv.y, kv.z, kv.w};
    float s = v[0] + v[1] + v[2] + v[3];
    float mean = block_sum_256(s, red) * (1.0f / Dd);
    float sq = 0.f;
#pragma unroll
    for (int j = 0; j < 4; ++j) {
        v[j] -= mean;
        sq += v[j] * v[j];
    }
    float var = block_sum_256(sq, red) * (1.0f / Dd);
    float rs = rsqrtf(var + LN_EPS);
#pragma unroll
    for (int j = 0; j < 4; ++j) {
        int d = tid * 4 + j;
        yrow[d] = v[j] * rs * klnw[d];
    }
    __syncthreads();
    const int d0 = tid * 4;
    const int hh = d0 >> 6;
    const int dh0 = d0 & 63;
    ushort4 pk;
    unsigned short* pp = (unsigned short*)&pk;
#pragma unroll
    for (int j = 0; j < 4; ++j) {
        int d = d0 + j;
        int dh = dh0 + j;
        int i = dh & 31;
        float invf = powf(10000.0f, -(float)i * (1.0f / 32.0f));
        float ang = (float)l * invf;
        float sn, cs;
        sincosf(ang, &sn, &cs);
        float rot = (dh < 32) ? -yrow[d + 32] : yrow[d - 32];
        pp[j] = f2bf(yrow[d] * cs + rot * sn);
    }
    *(ushort4*)(kt + (((size_t)(b * Hh + hh)) * Ls + l) * DHh + dh0) = pk;
}

// ---------------- 4c. V path: +lora, bf16 ----------------
__global__ __launch_bounds__(256) void v_final_kernel(const float* __restrict__ qkv,
                                                      const float* __restrict__ vtmp,
                                                      const float* __restrict__ vb,
                                                      unsigned short* __restrict__ vt) {
    const int row = blockIdx.x;
    const int b = row >> 11;
    const int l = row & (Ls - 1);
    const int tid = threadIdx.x;
    __shared__ float tl[Rr];
    if (tid < Rr) tl[tid] = vtmp[(size_t)row * Rr + tid];
    __syncthreads();
    float4 vv = *(const float4*)(qkv + (size_t)row * (3 * Dd) + 2 * Dd + tid * 4);
    float v[4] = {vv.x, vv.y, vv.z, vv.w};
    const int d0 = tid * 4;
    const int hh = d0 >> 6;
    const int dh0 = d0 & 63;
    ushort4 pk;
    unsigned short* pp = (unsigned short*)&pk;
#pragma unroll
    for (int j = 0; j < 4; ++j) {
        int d = d0 + j;
        float s = 0.f;
        for (int r = 0; r < Rr; r += 4) {
            float4 bv = *(const float4*)(vb + (size_t)d * Rr + r);
            s += tl[r] * bv.x + tl[r + 1] * bv.y + tl[r + 2] * bv.z + tl[r + 3] * bv.w;
        }
        pp[j] = f2bf(v[j] + LORA_SCALE * s);
    }
    *(ushort4*)(vt + (((size_t)(b * Hh + hh)) * Ls + l) * DHh + dh0) = pk;
}

// ---------------- 5. MFMA flash attention ----------------
// grid (L/64, H, B), block 256 (4 waves). Wave w owns q rows q0+w*16 .. +15.
// K-tiles of 64 keys; seq_id-sorted block skipping.
constexpr int PITCH = 72;  // bf16 elements per LDS row (16B pad -> 2-way banks)

__global__ __launch_bounds__(256) void attn_kernel(const unsigned short* __restrict__ qt,
                                                   const unsigned short* __restrict__ kt,
                                                   const unsigned short* __restrict__ vt,
                                                   const int* __restrict__ seq_id,
                                                   float* __restrict__ ctx) {
    const int q0 = blockIdx.x * 64;
    const int h = blockIdx.y;
    const int b = blockIdx.z;
    const size_t base = ((size_t)(b * Hh + h)) * Ls * DHh;
    const int* sid = seq_id + (size_t)b * Ls;

    __shared__ short Qs[64][PITCH];
    __shared__ short Ks[64][PITCH];
    __shared__ short Vt[64][PITCH];   // transposed: Vt[dh][key]
    __shared__ short Ps[4][16][PITCH];
    __shared__ int sq_s[64];

    const int tid = threadIdx.x;
    const int w = tid >> 6;
    const int lane = tid & 63;
    const int quad = lane >> 4;
    const int l15 = lane & 15;

    // stage Q tile (64 rows x 64 dh) + q seq ids
#pragma unroll
    for (int j = 0; j < 2; ++j) {
        int g = tid + j * 256;
        int kk = g >> 3;
        int c0 = (g & 7) * 8;
        *(uint4*)&Qs[kk][c0] = *(const uint4*)(qt + base + (size_t)(q0 + kk) * DHh + c0);
    }
    if (tid < 64) sq_s[tid] = sid[q0 + tid];
    const int qmin = sid[q0];
    const int qmax = sid[q0 + 63];

    // per-wave A frags of Q (reused every tile)
    float m_r[4], l_r[4];
    f32x4 O[4];
#pragma unroll
    for (int r = 0; r < 4; ++r) { m_r[r] = -1e30f; l_r[r] = 0.f; O[r] = f32x4{0.f, 0.f, 0.f, 0.f}; }

    for (int k0 = 0; k0 < Ls; k0 += 64) {
        const int kmin = sid[k0];
        const int kmax = sid[k0 + 63];
        if (kmin > qmax) break;      // sorted: nothing later overlaps either
        if (kmax < qmin) continue;   // this tile fully masked

        __syncthreads();  // previous tile's readers done before overwrite
        // stage K (row-major) and V (transposed)
#pragma unroll
        for (int j = 0; j < 2; ++j) {
            int g = tid + j * 256;
            int kk = g >> 3;
            int c0 = (g & 7) * 8;
            *(uint4*)&Ks[kk][c0] = *(const uint4*)(kt + base + (size_t)(k0 + kk) * DHh + c0);
        }
#pragma unroll
        for (int j = 0; j < 2; ++j) {
            int dh0 = (tid >> 6) * 16 + j * 8;
            int kk = tid & 63;
            uint4 vv = *(const uint4*)(vt + base + (size_t)(k0 + kk) * DHh + dh0);
            const unsigned short* pv = (const unsigned short*)&vv;
#pragma unroll
            for (int i = 0; i < 8; ++i) Vt[dh0 + i][kk] = (short)pv[i];
        }
        __syncthreads();

        // ---- S = Q K^T for this wave's 16 q rows x 64 keys ----
        const int qrow = w * 16 + l15;
        bf16x8 a0 = *(const bf16x8*)&Qs[qrow][quad * 8];
        bf16x8 a1 = *(const bf16x8*)&Qs[qrow][32 + quad * 8];
        f32x4 s[4];
#pragma unroll
        for (int kg = 0; kg < 4; ++kg) {
            bf16x8 b0 = *(const bf16x8*)&Ks[kg * 16 + l15][quad * 8];
            bf16x8 b1 = *(const bf16x8*)&Ks[kg * 16 + l15][32 + quad * 8];
            f32x4 acc = {0.f, 0.f, 0.f, 0.f};
            acc = __builtin_amdgcn_mfma_f32_16x16x32_bf16(a0, b0, acc, 0, 0, 0);
            acc = __builtin_amdgcn_mfma_f32_16x16x32_bf16(a1, b1, acc, 0, 0, 0);
            s[kg] = acc;
        }
        // scale to log2 domain + mask.  C layout: col=kg*16+l15 (key), row=quad*4+r (q)
        int sqv[4];
#pragma unroll
        for (int r = 0; r < 4; ++r) sqv[r] = sq_s[w * 16 + quad * 4 + r];
#pragma unroll
        for (int kg = 0; kg < 4; ++kg) {
            int skv = sid[k0 + kg * 16 + l15];
#pragma unroll
            for (int r = 0; r < 4; ++r) {
                float v = s[kg][r] * (ATTN_SCALE * LOG2E);
                s[kg][r] = (sqv[r] != skv) ? -3.0e38f : v;
            }
        }
        // row max over 64 keys (4 kg regs + 16 lanes of the quad)
        float tmax[4], tsum[4];
#pragma unroll
        for (int r = 0; r < 4; ++r)
            tmax[r] = fmaxf(fmaxf(s[0][r], s[1][r]), fmaxf(s[2][r], s[3][r]));
#pragma unroll
        for (int off = 1; off < 16; off <<= 1)
#pragma unroll
            for (int r = 0; r < 4; ++r)
                tmax[r] = fmaxf(tmax[r], __shfl_xor(tmax[r], off, 64));
        float alpha[4];
#pragma unroll
        for (int r = 0; r < 4; ++r) {
            float mn = fmaxf(m_r[r], tmax[r]);
            alpha[r] = exp2f(m_r[r] - mn);
            m_r[r] = mn;
        }
#pragma unroll
        for (int kg = 0; kg < 4; ++kg)
#pragma unroll
            for (int r = 0; r < 4; ++r)
                s[kg][r] = exp2f(s[kg][r] - m_r[r]);
#pragma unroll
        for (int r = 0; r < 4; ++r)
            tsum[r] = s[0][r] + s[1][r] + s[2][r] + s[3][r];
#pragma unroll
        for (int off = 1; off < 16; off <<= 1)
#pragma unroll
            for (int r = 0; r < 4; ++r)
                tsum[r] += __shfl_xor(tsum[r], off, 64);
#pragma unroll
        for (int r = 0; r < 4; ++r) {
            l_r[r] = l_r[r] * alpha[r] + tsum[r];
            O[0][r] *= alpha[r]; O[1][r] *= alpha[r]; O[2][r] *= alpha[r]; O[3][r] *= alpha[r];
        }
        // write P (bf16) to this wave's LDS buffer, C-layout -> row-major
#pragma unroll
        for (int kg = 0; kg < 4; ++kg)
#pragma unroll
            for (int r = 0; r < 4; ++r)
                Ps[w][quad * 4 + r][kg * 16 + l15] = (short)f2bf(s[kg][r]);
        // ---- O += P V ----
        bf16x8 pa0 = *(const bf16x8*)&Ps[w][l15][quad * 8];
        bf16x8 pa1 = *(const bf16x8*)&Ps[w][l15][32 + quad * 8];
#pragma unroll
        for (int ng = 0; ng < 4; ++ng) {
            bf16x8 vb0 = *(const bf16x8*)&Vt[ng * 16 + l15][quad * 8];
            bf16x8 vb1 = *(const bf16x8*)&Vt[ng * 16 + l15][32 + quad * 8];
            O[ng] = __builtin_amdgcn_mfma_f32_16x16x32_bf16(pa0, vb0, O[ng], 0, 0, 0);
            O[ng] = __builtin_amdgcn_mfma_f32_16x16x32_bf16(pa1, vb1, O[ng], 0, 0, 0);
        }
    }

    // epilogue: normalize, write ctx fp32 [BL, D]
    float inv_l[4];
#pragma unroll
    for (int r = 0; r < 4; ++r) inv_l[r] = 1.0f / l_r[r];
#pragma unroll
    for (int ng = 0; ng < 4; ++ng)
#pragma unroll
        for (int r = 0; r < 4; ++r) {
            int q = q0 + w * 16 + quad * 4 + r;
            ctx[((size_t)b * Ls + q) * Dd + h * DHh + ng * 16 + l15] = O[ng][r] * inv_l[r];
        }
}

// ---------------- launcher ----------------
extern "C" void kernel_launch(void* const* d_in, const int* in_sizes, int n_in,
                              void* d_out, int out_size, void* d_ws, size_t ws_size,
                              hipStream_t stream) {
    const float* x = (const float*)d_in[0];
    const int* seq_id = (const int*)d_in[1];
    const float* ln_w = (const float*)d_in[2];
    const float* ln_b = (const float*)d_in[3];
    const float* w_qkv = (const float*)d_in[4];
    const float* q_lora_a = (const float*)d_in[5];
    const float* q_lora_b = (const float*)d_in[6];
    const float* v_lora_a = (const float*)d_in[7];
    const float* v_lora_b = (const float*)d_in[8];
    const float* q_ln_w = (const float*)d_in[9];
    const float* k_ln_w = (const float*)d_in[10];
    const float* w_out = (const float*)d_in[11];
    float* out = (float*)d_out;

    float* ws = (float*)d_ws;
    const size_t SZ = (size_t)BL * Dd;        // 4M elements
    float* h = ws;                            // [BL, D] fp32
    float* qkv = ws + SZ;                     // [BL, 3D] fp32
    float* qtmp = ws + 4 * SZ;                // [BL, R]
    float* vtmp = qtmp + (size_t)BL * Rr;
    unsigned short* qt = (unsigned short*)(ws + 5 * SZ);  // bf16 [B,H,L,DH]
    unsigned short* kt = qt + SZ;
    unsigned short* vt = kt + SZ;
    float* ctx = h;                           // reuse: h dead after lora_tmp

    ln_x_kernel<<<BL, 256, 0, stream>>>(x, ln_w, ln_b, h);
    {
        dim3 g(3 * Dd / 64, BL / 64);
        gemm_abt<<<g, 256, 0, stream>>>(h, w_qkv, qkv, BL, 3 * Dd, Dd);
    }
    lora_tmp_kernel<<<BL, 256, 0, stream>>>(h, q_lora_a, v_lora_a, qtmp, vtmp);
    q_final_kernel<<<BL, 256, 0, stream>>>(qkv, qtmp, q_lora_b, q_ln_w, qt);
    k_final_kernel<<<BL, 256, 0, stream>>>(qkv, k_ln_w, kt);
    v_final_kernel<<<BL, 256, 0, stream>>>(qkv, vtmp, v_lora_b, vt);
    {
        dim3 g(Ls / 64, Hh, Bb);
        attn_kernel<<<g, 256, 0, stream>>>(qt, kt, vt, seq_id, ctx);
    }
    {
        dim3 g(Dd / 64, BL / 64);
        gemm_abt<<<g, 256, 0, stream>>>(ctx, w_out, out, BL, Dd, Dd);
    }
}

// Round 3
// 609.465 us; speedup vs baseline: 5.2231x; 1.6486x over previous
//
#include <hip/hip_runtime.h>
#include <hip/hip_bf16.h>
#include <cmath>

// Problem constants (fixed by reference)
constexpr int Bb = 2;
constexpr int Ls = 2048;
constexpr int Dd = 1024;
constexpr int Hh = 16;
constexpr int DHh = 64;
constexpr int Rr = 32;
constexpr int BL = Bb * Ls;          // 4096
constexpr float LORA_SCALE = 2.0f;   // 64/32
constexpr float LN_EPS = 1e-5f;
constexpr float ATTN_SCALE = 0.125f; // 1/sqrt(64)
constexpr float LOG2E = 1.4426950408889634f;

typedef __attribute__((ext_vector_type(8))) short bf16x8;
typedef __attribute__((ext_vector_type(4))) float f32x4;

__device__ __forceinline__ unsigned short f2bf(float f) {
    __hip_bfloat16 b = __float2bfloat16(f);
    return *reinterpret_cast<unsigned short*>(&b);
}
__device__ __forceinline__ float bf2f(unsigned short u) {
    unsigned int x = ((unsigned int)u) << 16;
    return __uint_as_float(x);
}
__device__ __forceinline__ void async_copy16(const void* g, void* l) {
    __builtin_amdgcn_global_load_lds(
        (__attribute__((address_space(1))) void*)(void*)(size_t)g,
        (__attribute__((address_space(3))) void*)l, 16, 0, 0);
}

// ---------------- block-wide sum over 256 threads ----------------
__device__ __forceinline__ float block_sum_256(float v, float* red) {
#pragma unroll
    for (int o = 32; o > 0; o >>= 1) v += __shfl_down(v, o, 64);
    const int lane = threadIdx.x & 63;
    const int wid = threadIdx.x >> 6;
    if (lane == 0) red[wid] = v;
    __syncthreads();
    float s = red[0] + red[1] + red[2] + red[3];
    __syncthreads();
    return s;
}

// ---------------- 0. fp32 -> bf16 cast (weights) ----------------
__global__ __launch_bounds__(256) void cast_bf16_kernel(const float* __restrict__ src,
                                                        unsigned short* __restrict__ dst,
                                                        int n) {
    int i = (blockIdx.x * 256 + threadIdx.x) * 4;
    if (i < n) {
        float4 v = *(const float4*)(src + i);
        ushort4 o;
        o.x = f2bf(v.x); o.y = f2bf(v.y); o.z = f2bf(v.z); o.w = f2bf(v.w);
        *(ushort4*)(dst + i) = o;
    }
}

// ---------------- 1. LayerNorm(x) -> h (bf16) ----------------
__global__ __launch_bounds__(256) void ln_x_kernel(const float* __restrict__ x,
                                                   const float* __restrict__ w,
                                                   const float* __restrict__ b,
                                                   unsigned short* __restrict__ hb) {
    const int row = blockIdx.x;
    const int tid = threadIdx.x;
    __shared__ float red[4];
    float4 xv = *(const float4*)(x + (size_t)row * Dd + tid * 4);
    float v[4] = {xv.x, xv.y, xv.z, xv.w};
    float s = v[0] + v[1] + v[2] + v[3];
    float mean = block_sum_256(s, red) * (1.0f / Dd);
    float sq = 0.f;
#pragma unroll
    for (int j = 0; j < 4; ++j) {
        v[j] -= mean;
        sq += v[j] * v[j];
    }
    float var = block_sum_256(sq, red) * (1.0f / Dd);
    float rs = rsqrtf(var + LN_EPS);
    ushort4 o;
    unsigned short* op = (unsigned short*)&o;
#pragma unroll
    for (int j = 0; j < 4; ++j) {
        int d = tid * 4 + j;
        op[j] = f2bf(v[j] * rs * w[d] + b[d]);
    }
    *(ushort4*)(hb + (size_t)row * Dd + tid * 4) = o;
}

// ---------------- 2. MFMA GEMM: C[M,N] = A[M,K] * B[N,K]^T ----------------
// A,B bf16 row-major; C fp32. 128x128 tile, BK=64, 256 thr (4 waves, 2x2 of 64x64).
// LDS chunks (16B) XOR-swizzled: LDS[row][jl] holds global chunk jl^(row&7).
__global__ __launch_bounds__(256) void gemm_bt_mfma(const unsigned short* __restrict__ A,
                                                    const unsigned short* __restrict__ B,
                                                    float* __restrict__ C,
                                                    int M, int N, int K) {
    __shared__ short As[128 * 64];
    __shared__ short Bs[128 * 64];
    const int tid = threadIdx.x;
    const int w = tid >> 6, lane = tid & 63, quad = lane >> 4, l15 = lane & 15;
    const int m0 = blockIdx.y * 128, n0 = blockIdx.x * 128;
    const int wm = (w & 1) * 64, wn = (w >> 1) * 64;
    f32x4 acc[4][4];
#pragma unroll
    for (int i = 0; i < 4; ++i)
#pragma unroll
        for (int j = 0; j < 4; ++j) acc[i][j] = f32x4{0.f, 0.f, 0.f, 0.f};

    for (int k0 = 0; k0 < K; k0 += 64) {
#pragma unroll
        for (int j = 0; j < 4; ++j) {
            int c = tid + j * 256;           // 16B-chunk index in tile
            int row = c >> 3;
            int jg = (c & 7) ^ (row & 7);    // fetch swizzled global chunk
            async_copy16(A + (size_t)(m0 + row) * K + k0 + jg * 8, As + c * 8);
        }
#pragma unroll
        for (int j = 0; j < 4; ++j) {
            int c = tid + j * 256;
            int row = c >> 3;
            int jg = (c & 7) ^ (row & 7);
            async_copy16(B + (size_t)(n0 + row) * K + k0 + jg * 8, Bs + c * 8);
        }
        __syncthreads();
#pragma unroll
        for (int ks = 0; ks < 2; ++ks) {
            bf16x8 a[4], b[4];
#pragma unroll
            for (int mi = 0; mi < 4; ++mi) {
                int row = wm + mi * 16 + l15;
                int ch = (ks * 4 + quad) ^ (row & 7);
                a[mi] = *(const bf16x8*)&As[row * 64 + ch * 8];
            }
#pragma unroll
            for (int ni = 0; ni < 4; ++ni) {
                int row = wn + ni * 16 + l15;
                int ch = (ks * 4 + quad) ^ (row & 7);
                b[ni] = *(const bf16x8*)&Bs[row * 64 + ch * 8];
            }
#pragma unroll
            for (int mi = 0; mi < 4; ++mi)
#pragma unroll
                for (int ni = 0; ni < 4; ++ni)
                    acc[mi][ni] = __builtin_amdgcn_mfma_f32_16x16x32_bf16(a[mi], b[ni], acc[mi][ni], 0, 0, 0);
        }
        __syncthreads();
    }
#pragma unroll
    for (int mi = 0; mi < 4; ++mi)
#pragma unroll
        for (int ni = 0; ni < 4; ++ni)
#pragma unroll
            for (int r = 0; r < 4; ++r)
                C[(size_t)(m0 + wm + mi * 16 + quad * 4 + r) * N + n0 + wn + ni * 16 + l15] =
                    acc[mi][ni][r];
}

// ---------------- 3. LoRA down-proj (h bf16) ----------------
__global__ __launch_bounds__(256) void lora_tmp_kernel(const unsigned short* __restrict__ hb,
                                                       const float* __restrict__ qa,
                                                       const float* __restrict__ va,
                                                       float* __restrict__ qtmp,
                                                       float* __restrict__ vtmp) {
    const int row = blockIdx.x;
    const int tid = threadIdx.x;
    __shared__ float hr[Dd];
    __shared__ float sred[256];
    ushort4 hv = *(const ushort4*)(hb + (size_t)row * Dd + tid * 4);
    hr[tid * 4 + 0] = bf2f(hv.x);
    hr[tid * 4 + 1] = bf2f(hv.y);
    hr[tid * 4 + 2] = bf2f(hv.z);
    hr[tid * 4 + 3] = bf2f(hv.w);
    __syncthreads();
    const int out_id = tid >> 2;   // 0..63 (32 q + 32 v)
    const int part = tid & 3;
    const float* a = (out_id < Rr) ? (qa + (size_t)out_id * Dd)
                                   : (va + (size_t)(out_id - Rr) * Dd);
    float partial = 0.f;
    const int dbase = part * 256;
    for (int d = 0; d < 256; d += 4) {
        float4 av = *(const float4*)(a + dbase + d);
        partial += hr[dbase + d] * av.x + hr[dbase + d + 1] * av.y +
                   hr[dbase + d + 2] * av.z + hr[dbase + d + 3] * av.w;
    }
    sred[tid] = partial;
    __syncthreads();
    if (part == 0) {
        float t = sred[tid] + sred[tid + 1] + sred[tid + 2] + sred[tid + 3];
        if (out_id < Rr) qtmp[(size_t)row * Rr + out_id] = t;
        else vtmp[(size_t)row * Rr + (out_id - Rr)] = t;
    }
}

// ---------------- 4a. Q path: +lora, LN, RoPE, bf16 [B,H,L,DH] ----------------
__global__ __launch_bounds__(256) void q_final_kernel(const float* __restrict__ qkv,
                                                      const float* __restrict__ qtmp,
                                                      const float* __restrict__ qb,
                                                      const float* __restrict__ qlnw,
                                                      unsigned short* __restrict__ qt) {
    const int row = blockIdx.x;
    const int b = row >> 11;
    const int l = row & (Ls - 1);
    const int tid = threadIdx.x;
    __shared__ float tl[Rr];
    __shared__ float red[4];
    __shared__ float yrow[Dd];
    if (tid < Rr) tl[tid] = qtmp[(size_t)row * Rr + tid];
    __syncthreads();
    float4 qv = *(const float4*)(qkv + (size_t)row * (3 * Dd) + tid * 4);
    float v[4] = {qv.x, qv.y, qv.z, qv.w};
#pragma unroll
    for (int j = 0; j < 4; ++j) {
        int d = tid * 4 + j;
        float s = 0.f;
        for (int r = 0; r < Rr; r += 4) {
            float4 bv = *(const float4*)(qb + (size_t)d * Rr + r);
            s += tl[r] * bv.x + tl[r + 1] * bv.y + tl[r + 2] * bv.z + tl[r + 3] * bv.w;
        }
        v[j] += LORA_SCALE * s;
    }
    float s = v[0] + v[1] + v[2] + v[3];
    float mean = block_sum_256(s, red) * (1.0f / Dd);
    float sq = 0.f;
#pragma unroll
    for (int j = 0; j < 4; ++j) {
        v[j] -= mean;
        sq += v[j] * v[j];
    }
    float var = block_sum_256(sq, red) * (1.0f / Dd);
    float rs = rsqrtf(var + LN_EPS);
#pragma unroll
    for (int j = 0; j < 4; ++j) {
        int d = tid * 4 + j;
        yrow[d] = v[j] * rs * qlnw[d];
    }
    __syncthreads();
    const int d0 = tid * 4;
    const int hh = d0 >> 6;
    const int dh0 = d0 & 63;
    ushort4 pk;
    unsigned short* pp = (unsigned short*)&pk;
#pragma unroll
    for (int j = 0; j < 4; ++j) {
        int d = d0 + j;
        int dh = dh0 + j;
        int i = dh & 31;
        float invf = powf(10000.0f, -(float)i * (1.0f / 32.0f));
        float ang = (float)l * invf;
        float sn, cs;
        sincosf(ang, &sn, &cs);
        float rot = (dh < 32) ? -yrow[d + 32] : yrow[d - 32];
        pp[j] = f2bf(yrow[d] * cs + rot * sn);
    }
    *(ushort4*)(qt + (((size_t)(b * Hh + hh)) * Ls + l) * DHh + dh0) = pk;
}

// ---------------- 4b. K path: LN, RoPE, bf16 ----------------
__global__ __launch_bounds__(256) void k_final_kernel(const float* __restrict__ qkv,
                                                      const float* __restrict__ klnw,
                                                      unsigned short* __restrict__ kt) {
    const int row = blockIdx.x;
    const int b = row >> 11;
    const int l = row & (Ls - 1);
    const int tid = threadIdx.x;
    __shared__ float red[4];
    __shared__ float yrow[Dd];
    float4 kv = *(const float4*)(qkv + (size_t)row * (3 * Dd) + Dd + tid * 4);
    float v[4] = {kv.x, kv.y, kv.z, kv.w};
    float s = v[0] + v[1] + v[2] + v[3];
    float mean = block_sum_256(s, red) * (1.0f / Dd);
    float sq = 0.f;
#pragma unroll
    for (int j = 0; j < 4; ++j) {
        v[j] -= mean;
        sq += v[j] * v[j];
    }
    float var = block_sum_256(sq, red) * (1.0f / Dd);
    float rs = rsqrtf(var + LN_EPS);
#pragma unroll
    for (int j = 0; j < 4; ++j) {
        int d = tid * 4 + j;
        yrow[d] = v[j] * rs * klnw[d];
    }
    __syncthreads();
    const int d0 = tid * 4;
    const int hh = d0 >> 6;
    const int dh0 = d0 & 63;
    ushort4 pk;
    unsigned short* pp = (unsigned short*)&pk;
#pragma unroll
    for (int j = 0; j < 4; ++j) {
        int d = d0 + j;
        int dh = dh0 + j;
        int i = dh & 31;
        float invf = powf(10000.0f, -(float)i * (1.0f / 32.0f));
        float ang = (float)l * invf;
        float sn, cs;
        sincosf(ang, &sn, &cs);
        float rot = (dh < 32) ? -yrow[d + 32] : yrow[d - 32];
        pp[j] = f2bf(yrow[d] * cs + rot * sn);
    }
    *(ushort4*)(kt + (((size_t)(b * Hh + hh)) * Ls + l) * DHh + dh0) = pk;
}

// ---------------- 4c. V path: +lora, bf16 ----------------
__global__ __launch_bounds__(256) void v_final_kernel(const float* __restrict__ qkv,
                                                      const float* __restrict__ vtmp,
                                                      const float* __restrict__ vb,
                                                      unsigned short* __restrict__ vt) {
    const int row = blockIdx.x;
    const int b = row >> 11;
    const int l = row & (Ls - 1);
    const int tid = threadIdx.x;
    __shared__ float tl[Rr];
    if (tid < Rr) tl[tid] = vtmp[(size_t)row * Rr + tid];
    __syncthreads();
    float4 vv = *(const float4*)(qkv + (size_t)row * (3 * Dd) + 2 * Dd + tid * 4);
    float v[4] = {vv.x, vv.y, vv.z, vv.w};
    const int d0 = tid * 4;
    const int hh = d0 >> 6;
    const int dh0 = d0 & 63;
    ushort4 pk;
    unsigned short* pp = (unsigned short*)&pk;
#pragma unroll
    for (int j = 0; j < 4; ++j) {
        int d = d0 + j;
        float s = 0.f;
        for (int r = 0; r < Rr; r += 4) {
            float4 bv = *(const float4*)(vb + (size_t)d * Rr + r);
            s += tl[r] * bv.x + tl[r + 1] * bv.y + tl[r + 2] * bv.z + tl[r + 3] * bv.w;
        }
        pp[j] = f2bf(v[j] + LORA_SCALE * s);
    }
    *(ushort4*)(vt + (((size_t)(b * Hh + hh)) * Ls + l) * DHh + dh0) = pk;
}

// ---------------- 5. MFMA flash attention ----------------
// grid (L/64, H, B), block 256 (4 waves). Wave w owns q rows q0+w*16 .. +15.
constexpr int PITCH = 72;  // bf16 elements per LDS row (16B pad -> 2-way banks)

__global__ __launch_bounds__(256) void attn_kernel(const unsigned short* __restrict__ qt,
                                                   const unsigned short* __restrict__ kt,
                                                   const unsigned short* __restrict__ vt,
                                                   const int* __restrict__ seq_id,
                                                   unsigned short* __restrict__ ctxb) {
    const int q0 = blockIdx.x * 64;
    const int h = blockIdx.y;
    const int b = blockIdx.z;
    const size_t base = ((size_t)(b * Hh + h)) * Ls * DHh;
    const int* sid = seq_id + (size_t)b * Ls;

    __shared__ short Qs[64][PITCH];
    __shared__ short Ks[64][PITCH];
    __shared__ short Vt[64][PITCH];   // transposed: Vt[dh][key]
    __shared__ short Ps[4][16][PITCH];
    __shared__ int sq_s[64];

    const int tid = threadIdx.x;
    const int w = tid >> 6;
    const int lane = tid & 63;
    const int quad = lane >> 4;
    const int l15 = lane & 15;

#pragma unroll
    for (int j = 0; j < 2; ++j) {
        int g = tid + j * 256;
        int kk = g >> 3;
        int c0 = (g & 7) * 8;
        *(uint4*)&Qs[kk][c0] = *(const uint4*)(qt + base + (size_t)(q0 + kk) * DHh + c0);
    }
    if (tid < 64) sq_s[tid] = sid[q0 + tid];
    const int qmin = sid[q0];
    const int qmax = sid[q0 + 63];

    float m_r[4], l_r[4];
    f32x4 O[4];
#pragma unroll
    for (int r = 0; r < 4; ++r) { m_r[r] = -1e30f; l_r[r] = 0.f; O[r] = f32x4{0.f, 0.f, 0.f, 0.f}; }

    for (int k0 = 0; k0 < Ls; k0 += 64) {
        const int kmin = sid[k0];
        const int kmax = sid[k0 + 63];
        if (kmin > qmax) break;      // sorted: nothing later overlaps either
        if (kmax < qmin) continue;   // this tile fully masked

        __syncthreads();
#pragma unroll
        for (int j = 0; j < 2; ++j) {
            int g = tid + j * 256;
            int kk = g >> 3;
            int c0 = (g & 7) * 8;
            *(uint4*)&Ks[kk][c0] = *(const uint4*)(kt + base + (size_t)k0 * DHh + (size_t)kk * DHh + c0);
        }
#pragma unroll
        for (int j = 0; j < 2; ++j) {
            int dh0 = (tid >> 6) * 16 + j * 8;
            int kk = tid & 63;
            uint4 vv = *(const uint4*)(vt + base + (size_t)(k0 + kk) * DHh + dh0);
            const unsigned short* pv = (const unsigned short*)&vv;
#pragma unroll
            for (int i = 0; i < 8; ++i) Vt[dh0 + i][kk] = (short)pv[i];
        }
        __syncthreads();

        const int qrow = w * 16 + l15;
        bf16x8 a0 = *(const bf16x8*)&Qs[qrow][quad * 8];
        bf16x8 a1 = *(const bf16x8*)&Qs[qrow][32 + quad * 8];
        f32x4 s[4];
#pragma unroll
        for (int kg = 0; kg < 4; ++kg) {
            bf16x8 b0 = *(const bf16x8*)&Ks[kg * 16 + l15][quad * 8];
            bf16x8 b1 = *(const bf16x8*)&Ks[kg * 16 + l15][32 + quad * 8];
            f32x4 acc = {0.f, 0.f, 0.f, 0.f};
            acc = __builtin_amdgcn_mfma_f32_16x16x32_bf16(a0, b0, acc, 0, 0, 0);
            acc = __builtin_amdgcn_mfma_f32_16x16x32_bf16(a1, b1, acc, 0, 0, 0);
            s[kg] = acc;
        }
        int sqv[4];
#pragma unroll
        for (int r = 0; r < 4; ++r) sqv[r] = sq_s[w * 16 + quad * 4 + r];
#pragma unroll
        for (int kg = 0; kg < 4; ++kg) {
            int skv = sid[k0 + kg * 16 + l15];
#pragma unroll
            for (int r = 0; r < 4; ++r) {
                float v = s[kg][r] * (ATTN_SCALE * LOG2E);
                s[kg][r] = (sqv[r] != skv) ? -3.0e38f : v;
            }
        }
        float tmax[4], tsum[4];
#pragma unroll
        for (int r = 0; r < 4; ++r)
            tmax[r] = fmaxf(fmaxf(s[0][r], s[1][r]), fmaxf(s[2][r], s[3][r]));
#pragma unroll
        for (int off = 1; off < 16; off <<= 1)
#pragma unroll
            for (int r = 0; r < 4; ++r)
                tmax[r] = fmaxf(tmax[r], __shfl_xor(tmax[r], off, 64));
        float alpha[4];
#pragma unroll
        for (int r = 0; r < 4; ++r) {
            float mn = fmaxf(m_r[r], tmax[r]);
            alpha[r] = exp2f(m_r[r] - mn);
            m_r[r] = mn;
        }
#pragma unroll
        for (int kg = 0; kg < 4; ++kg)
#pragma unroll
            for (int r = 0; r < 4; ++r)
                s[kg][r] = exp2f(s[kg][r] - m_r[r]);
#pragma unroll
        for (int r = 0; r < 4; ++r)
            tsum[r] = s[0][r] + s[1][r] + s[2][r] + s[3][r];
#pragma unroll
        for (int off = 1; off < 16; off <<= 1)
#pragma unroll
            for (int r = 0; r < 4; ++r)
                tsum[r] += __shfl_xor(tsum[r], off, 64);
#pragma unroll
        for (int r = 0; r < 4; ++r) {
            l_r[r] = l_r[r] * alpha[r] + tsum[r];
            O[0][r] *= alpha[r]; O[1][r] *= alpha[r]; O[2][r] *= alpha[r]; O[3][r] *= alpha[r];
        }
#pragma unroll
        for (int kg = 0; kg < 4; ++kg)
#pragma unroll
            for (int r = 0; r < 4; ++r)
                Ps[w][quad * 4 + r][kg * 16 + l15] = (short)f2bf(s[kg][r]);
        bf16x8 pa0 = *(const bf16x8*)&Ps[w][l15][quad * 8];
        bf16x8 pa1 = *(const bf16x8*)&Ps[w][l15][32 + quad * 8];
#pragma unroll
        for (int ng = 0; ng < 4; ++ng) {
            bf16x8 vb0 = *(const bf16x8*)&Vt[ng * 16 + l15][quad * 8];
            bf16x8 vb1 = *(const bf16x8*)&Vt[ng * 16 + l15][32 + quad * 8];
            O[ng] = __builtin_amdgcn_mfma_f32_16x16x32_bf16(pa0, vb0, O[ng], 0, 0, 0);
            O[ng] = __builtin_amdgcn_mfma_f32_16x16x32_bf16(pa1, vb1, O[ng], 0, 0, 0);
        }
    }

    float inv_l[4];
#pragma unroll
    for (int r = 0; r < 4; ++r) inv_l[r] = 1.0f / l_r[r];
#pragma unroll
    for (int ng = 0; ng < 4; ++ng)
#pragma unroll
        for (int r = 0; r < 4; ++r) {
            int q = q0 + w * 16 + quad * 4 + r;
            ctxb[((size_t)b * Ls + q) * Dd + h * DHh + ng * 16 + l15] = f2bf(O[ng][r] * inv_l[r]);
        }
}

// ---------------- launcher ----------------
extern "C" void kernel_launch(void* const* d_in, const int* in_sizes, int n_in,
                              void* d_out, int out_size, void* d_ws, size_t ws_size,
                              hipStream_t stream) {
    const float* x = (const float*)d_in[0];
    const int* seq_id = (const int*)d_in[1];
    const float* ln_w = (const float*)d_in[2];
    const float* ln_b = (const float*)d_in[3];
    const float* w_qkv = (const float*)d_in[4];
    const float* q_lora_a = (const float*)d_in[5];
    const float* q_lora_b = (const float*)d_in[6];
    const float* v_lora_a = (const float*)d_in[7];
    const float* v_lora_b = (const float*)d_in[8];
    const float* q_ln_w = (const float*)d_in[9];
    const float* k_ln_w = (const float*)d_in[10];
    const float* w_out = (const float*)d_in[11];
    float* out = (float*)d_out;

    const size_t SZ = (size_t)BL * Dd;        // 4M elements
    float* p = (float*)d_ws;
    float* qkv = p;            p += 3 * SZ;   // fp32 [BL, 3D]
    float* qtmp = p;           p += (size_t)BL * Rr;
    float* vtmp = p;           p += (size_t)BL * Rr;
    unsigned short* ub = (unsigned short*)p;
    unsigned short* hb = ub;   ub += SZ;      // bf16 [BL, D]
    unsigned short* qt = ub;   ub += SZ;      // bf16 [B,H,L,DH]
    unsigned short* kt = ub;   ub += SZ;
    unsigned short* vt = ub;   ub += SZ;
    unsigned short* ctxb = ub; ub += SZ;      // bf16 [BL, D]
    unsigned short* wqkvb = ub; ub += (size_t)3 * Dd * Dd;
    unsigned short* woutb = ub; ub += (size_t)Dd * Dd;

    cast_bf16_kernel<<<(3 * Dd * Dd) / 1024, 256, 0, stream>>>(w_qkv, wqkvb, 3 * Dd * Dd);
    cast_bf16_kernel<<<(Dd * Dd) / 1024, 256, 0, stream>>>(w_out, woutb, Dd * Dd);
    ln_x_kernel<<<BL, 256, 0, stream>>>(x, ln_w, ln_b, hb);
    {
        dim3 g(3 * Dd / 128, BL / 128);
        gemm_bt_mfma<<<g, 256, 0, stream>>>(hb, wqkvb, qkv, BL, 3 * Dd, Dd);
    }
    lora_tmp_kernel<<<BL, 256, 0, stream>>>(hb, q_lora_a, v_lora_a, qtmp, vtmp);
    q_final_kernel<<<BL, 256, 0, stream>>>(qkv, qtmp, q_lora_b, q_ln_w, qt);
    k_final_kernel<<<BL, 256, 0, stream>>>(qkv, k_ln_w, kt);
    v_final_kernel<<<BL, 256, 0, stream>>>(qkv, vtmp, v_lora_b, vt);
    {
        dim3 g(Ls / 64, Hh, Bb);
        attn_kernel<<<g, 256, 0, stream>>>(qt, kt, vt, seq_id, ctxb);
    }
    {
        dim3 g(Dd / 128, BL / 128);
        gemm_bt_mfma<<<g, 256, 0, stream>>>(ctxb, woutb, out, BL, Dd, Dd);
    }
}

// Round 4
// 575.153 us; speedup vs baseline: 5.5347x; 1.0597x over previous
//
#include <hip/hip_runtime.h>
#include <hip/hip_bf16.h>
#include <cmath>

// Problem constants (fixed by reference)
constexpr int Bb = 2;
constexpr int Ls = 2048;
constexpr int Dd = 1024;
constexpr int Hh = 16;
constexpr int DHh = 64;
constexpr int Rr = 32;
constexpr int BL = Bb * Ls;          // 4096
constexpr float LORA_SCALE = 2.0f;   // 64/32
constexpr float LN_EPS = 1e-5f;
constexpr float ATTN_SCALE = 0.125f; // 1/sqrt(64)
constexpr float LOG2E = 1.4426950408889634f;

typedef __attribute__((ext_vector_type(8))) short bf16x8;
typedef __attribute__((ext_vector_type(4))) float f32x4;

__device__ __forceinline__ unsigned short f2bf(float f) {
    __hip_bfloat16 b = __float2bfloat16(f);
    return *reinterpret_cast<unsigned short*>(&b);
}
__device__ __forceinline__ float bf2f(unsigned short u) {
    unsigned int x = ((unsigned int)u) << 16;
    return __uint_as_float(x);
}
__device__ __forceinline__ void async_copy16(const void* g, void* l) {
    __builtin_amdgcn_global_load_lds(
        (__attribute__((address_space(1))) void*)(void*)(size_t)g,
        (__attribute__((address_space(3))) void*)l, 16, 0, 0);
}

// ---------------- block-wide sum over 256 threads ----------------
__device__ __forceinline__ float block_sum_256(float v, float* red) {
#pragma unroll
    for (int o = 32; o > 0; o >>= 1) v += __shfl_down(v, o, 64);
    const int lane = threadIdx.x & 63;
    const int wid = threadIdx.x >> 6;
    if (lane == 0) red[wid] = v;
    __syncthreads();
    float s = red[0] + red[1] + red[2] + red[3];
    __syncthreads();
    return s;
}

// ---------------- 0a. fp32 -> bf16 cast (weights) ----------------
__global__ __launch_bounds__(256) void cast_bf16_kernel(const float* __restrict__ src,
                                                        unsigned short* __restrict__ dst,
                                                        int n) {
    int i = (blockIdx.x * 256 + threadIdx.x) * 4;
    if (i < n) {
        float4 v = *(const float4*)(src + i);
        ushort4 o;
        o.x = f2bf(v.x); o.y = f2bf(v.y); o.z = f2bf(v.z); o.w = f2bf(v.w);
        *(ushort4*)(dst + i) = o;
    }
}

// ---------------- 0b. RoPE table: cs/sn[l][f], f in 0..31 ----------------
__global__ __launch_bounds__(256) void rope_table_kernel(float* __restrict__ cs,
                                                         float* __restrict__ sn) {
    int i = blockIdx.x * 256 + threadIdx.x;   // over Ls*32
    int l = i >> 5;
    int f = i & 31;
    float invf = powf(10000.0f, -(float)f * (1.0f / 32.0f));
    float ang = (float)l * invf;
    float s, c;
    sincosf(ang, &s, &c);
    cs[i] = c;
    sn[i] = s;
}

// ---------------- 1. LayerNorm(x) -> h (bf16) ----------------
__global__ __launch_bounds__(256) void ln_x_kernel(const float* __restrict__ x,
                                                   const float* __restrict__ w,
                                                   const float* __restrict__ b,
                                                   unsigned short* __restrict__ hb) {
    const int row = blockIdx.x;
    const int tid = threadIdx.x;
    __shared__ float red[4];
    float4 xv = *(const float4*)(x + (size_t)row * Dd + tid * 4);
    float v[4] = {xv.x, xv.y, xv.z, xv.w};
    float s = v[0] + v[1] + v[2] + v[3];
    float mean = block_sum_256(s, red) * (1.0f / Dd);
    float sq = 0.f;
#pragma unroll
    for (int j = 0; j < 4; ++j) {
        v[j] -= mean;
        sq += v[j] * v[j];
    }
    float var = block_sum_256(sq, red) * (1.0f / Dd);
    float rs = rsqrtf(var + LN_EPS);
    ushort4 o;
    unsigned short* op = (unsigned short*)&o;
#pragma unroll
    for (int j = 0; j < 4; ++j) {
        int d = tid * 4 + j;
        op[j] = f2bf(v[j] * rs * w[d] + b[d]);
    }
    *(ushort4*)(hb + (size_t)row * Dd + tid * 4) = o;
}

// ---------------- 2. MFMA GEMM: C[M,N] = A[M,K] * B[N,K]^T ----------------
__global__ __launch_bounds__(256) void gemm_bt_mfma(const unsigned short* __restrict__ A,
                                                    const unsigned short* __restrict__ B,
                                                    float* __restrict__ C,
                                                    int M, int N, int K) {
    __shared__ short As[128 * 64];
    __shared__ short Bs[128 * 64];
    const int tid = threadIdx.x;
    const int w = tid >> 6, lane = tid & 63, quad = lane >> 4, l15 = lane & 15;
    const int m0 = blockIdx.y * 128, n0 = blockIdx.x * 128;
    const int wm = (w & 1) * 64, wn = (w >> 1) * 64;
    f32x4 acc[4][4];
#pragma unroll
    for (int i = 0; i < 4; ++i)
#pragma unroll
        for (int j = 0; j < 4; ++j) acc[i][j] = f32x4{0.f, 0.f, 0.f, 0.f};

    for (int k0 = 0; k0 < K; k0 += 64) {
#pragma unroll
        for (int j = 0; j < 4; ++j) {
            int c = tid + j * 256;
            int row = c >> 3;
            int jg = (c & 7) ^ (row & 7);
            async_copy16(A + (size_t)(m0 + row) * K + k0 + jg * 8, As + c * 8);
        }
#pragma unroll
        for (int j = 0; j < 4; ++j) {
            int c = tid + j * 256;
            int row = c >> 3;
            int jg = (c & 7) ^ (row & 7);
            async_copy16(B + (size_t)(n0 + row) * K + k0 + jg * 8, Bs + c * 8);
        }
        __syncthreads();
#pragma unroll
        for (int ks = 0; ks < 2; ++ks) {
            bf16x8 a[4], b[4];
#pragma unroll
            for (int mi = 0; mi < 4; ++mi) {
                int row = wm + mi * 16 + l15;
                int ch = (ks * 4 + quad) ^ (row & 7);
                a[mi] = *(const bf16x8*)&As[row * 64 + ch * 8];
            }
#pragma unroll
            for (int ni = 0; ni < 4; ++ni) {
                int row = wn + ni * 16 + l15;
                int ch = (ks * 4 + quad) ^ (row & 7);
                b[ni] = *(const bf16x8*)&Bs[row * 64 + ch * 8];
            }
#pragma unroll
            for (int mi = 0; mi < 4; ++mi)
#pragma unroll
                for (int ni = 0; ni < 4; ++ni)
                    acc[mi][ni] = __builtin_amdgcn_mfma_f32_16x16x32_bf16(a[mi], b[ni], acc[mi][ni], 0, 0, 0);
        }
        __syncthreads();
    }
#pragma unroll
    for (int mi = 0; mi < 4; ++mi)
#pragma unroll
        for (int ni = 0; ni < 4; ++ni)
#pragma unroll
            for (int r = 0; r < 4; ++r)
                C[(size_t)(m0 + wm + mi * 16 + quad * 4 + r) * N + n0 + wn + ni * 16 + l15] =
                    acc[mi][ni][r];
}

// ---------------- 3. fused LoRA-down + Q/K/V finalize ----------------
// one block per row (256 thr). Reads h-row (bf16) + qkv-row (fp32); emits
// qt/kt/vt bf16 [B,H,L,DH].
__global__ __launch_bounds__(256) void qkv_final_kernel(const unsigned short* __restrict__ hb,
                                                        const float* __restrict__ qkv,
                                                        const float* __restrict__ qa,
                                                        const float* __restrict__ va,
                                                        const float* __restrict__ qb,
                                                        const float* __restrict__ vb,
                                                        const float* __restrict__ qlnw,
                                                        const float* __restrict__ klnw,
                                                        const float* __restrict__ ropec,
                                                        const float* __restrict__ ropes,
                                                        unsigned short* __restrict__ qt,
                                                        unsigned short* __restrict__ kt,
                                                        unsigned short* __restrict__ vt) {
    const int row = blockIdx.x;
    const int b = row >> 11;
    const int l = row & (Ls - 1);
    const int tid = threadIdx.x;
    __shared__ float hr[Dd];
    __shared__ float yrow[Dd];
    __shared__ float sred[256];
    __shared__ float red[4];
    __shared__ float tlq[Rr], tlv[Rr];

    // h row -> LDS (fp32)
    {
        ushort4 hv = *(const ushort4*)(hb + (size_t)row * Dd + tid * 4);
        hr[tid * 4 + 0] = bf2f(hv.x);
        hr[tid * 4 + 1] = bf2f(hv.y);
        hr[tid * 4 + 2] = bf2f(hv.z);
        hr[tid * 4 + 3] = bf2f(hv.w);
    }
    __syncthreads();

    // LoRA down-proj: 64 outputs (32 q + 32 v), 4 threads each
    {
        const int out_id = tid >> 2;
        const int part = tid & 3;
        const float* a = (out_id < Rr) ? (qa + (size_t)out_id * Dd)
                                       : (va + (size_t)(out_id - Rr) * Dd);
        float partial = 0.f;
        const int dbase = part * 256;
        for (int d = 0; d < 256; d += 4) {
            float4 av = *(const float4*)(a + dbase + d);
            partial += hr[dbase + d] * av.x + hr[dbase + d + 1] * av.y +
                       hr[dbase + d + 2] * av.z + hr[dbase + d + 3] * av.w;
        }
        sred[tid] = partial;
    }
    __syncthreads();
    if ((tid & 3) == 0) {
        int out_id = tid >> 2;
        float t = sred[tid] + sred[tid + 1] + sred[tid + 2] + sred[tid + 3];
        if (out_id < Rr) tlq[out_id] = t;
        else tlv[out_id - Rr] = t;
    }
    __syncthreads();

    const int d0 = tid * 4;
    const int hh = d0 >> 6;
    const int dh0 = d0 & 63;
    // rope factors for the 4 elements (depend on dh % 32)
    float cs4[4], sn4[4];
#pragma unroll
    for (int j = 0; j < 4; ++j) {
        int f = (dh0 + j) & 31;
        cs4[j] = ropec[l * 32 + f];
        sn4[j] = ropes[l * 32 + f];
    }

    // ---- Q: +lora, LN, RoPE ----
    {
        float4 qv = *(const float4*)(qkv + (size_t)row * (3 * Dd) + d0);
        float v[4] = {qv.x, qv.y, qv.z, qv.w};
#pragma unroll
        for (int j = 0; j < 4; ++j) {
            int d = d0 + j;
            float s = 0.f;
            for (int r = 0; r < Rr; r += 4) {
                float4 bv = *(const float4*)(qb + (size_t)d * Rr + r);
                s += tlq[r] * bv.x + tlq[r + 1] * bv.y + tlq[r + 2] * bv.z + tlq[r + 3] * bv.w;
            }
            v[j] += LORA_SCALE * s;
        }
        float s = v[0] + v[1] + v[2] + v[3];
        float mean = block_sum_256(s, red) * (1.0f / Dd);
        float sq = 0.f;
#pragma unroll
        for (int j = 0; j < 4; ++j) {
            v[j] -= mean;
            sq += v[j] * v[j];
        }
        float var = block_sum_256(sq, red) * (1.0f / Dd);
        float rs = rsqrtf(var + LN_EPS);
#pragma unroll
        for (int j = 0; j < 4; ++j) yrow[d0 + j] = v[j] * rs * qlnw[d0 + j];
        __syncthreads();
        ushort4 pk;
        unsigned short* pp = (unsigned short*)&pk;
#pragma unroll
        for (int j = 0; j < 4; ++j) {
            int d = d0 + j;
            int dh = dh0 + j;
            float rot = (dh < 32) ? -yrow[d + 32] : yrow[d - 32];
            pp[j] = f2bf(yrow[d] * cs4[j] + rot * sn4[j]);
        }
        *(ushort4*)(qt + (((size_t)(b * Hh + hh)) * Ls + l) * DHh + dh0) = pk;
    }
    __syncthreads();  // yrow reuse

    // ---- K: LN, RoPE ----
    {
        float4 kv = *(const float4*)(qkv + (size_t)row * (3 * Dd) + Dd + d0);
        float v[4] = {kv.x, kv.y, kv.z, kv.w};
        float s = v[0] + v[1] + v[2] + v[3];
        float mean = block_sum_256(s, red) * (1.0f / Dd);
        float sq = 0.f;
#pragma unroll
        for (int j = 0; j < 4; ++j) {
            v[j] -= mean;
            sq += v[j] * v[j];
        }
        float var = block_sum_256(sq, red) * (1.0f / Dd);
        float rs = rsqrtf(var + LN_EPS);
#pragma unroll
        for (int j = 0; j < 4; ++j) yrow[d0 + j] = v[j] * rs * klnw[d0 + j];
        __syncthreads();
        ushort4 pk;
        unsigned short* pp = (unsigned short*)&pk;
#pragma unroll
        for (int j = 0; j < 4; ++j) {
            int d = d0 + j;
            int dh = dh0 + j;
            float rot = (dh < 32) ? -yrow[d + 32] : yrow[d - 32];
            pp[j] = f2bf(yrow[d] * cs4[j] + rot * sn4[j]);
        }
        *(ushort4*)(kt + (((size_t)(b * Hh + hh)) * Ls + l) * DHh + dh0) = pk;
    }

    // ---- V: +lora ----
    {
        float4 vv = *(const float4*)(qkv + (size_t)row * (3 * Dd) + 2 * Dd + d0);
        float v[4] = {vv.x, vv.y, vv.z, vv.w};
        ushort4 pk;
        unsigned short* pp = (unsigned short*)&pk;
#pragma unroll
        for (int j = 0; j < 4; ++j) {
            int d = d0 + j;
            float s = 0.f;
            for (int r = 0; r < Rr; r += 4) {
                float4 bv = *(const float4*)(vb + (size_t)d * Rr + r);
                s += tlv[r] * bv.x + tlv[r + 1] * bv.y + tlv[r + 2] * bv.z + tlv[r + 3] * bv.w;
            }
            pp[j] = f2bf(v[j] + LORA_SCALE * s);
        }
        *(ushort4*)(vt + (((size_t)(b * Hh + hh)) * Ls + l) * DHh + dh0) = pk;
    }
}

// ---------------- 5. MFMA flash attention ----------------
constexpr int PITCH = 72;  // bf16 elements per LDS row

__global__ __launch_bounds__(256) void attn_kernel(const unsigned short* __restrict__ qt,
                                                   const unsigned short* __restrict__ kt,
                                                   const unsigned short* __restrict__ vt,
                                                   const int* __restrict__ seq_id,
                                                   unsigned short* __restrict__ ctxb) {
    const int q0 = blockIdx.x * 64;
    const int h = blockIdx.y;
    const int b = blockIdx.z;
    const size_t base = ((size_t)(b * Hh + h)) * Ls * DHh;
    const int* sid = seq_id + (size_t)b * Ls;

    __shared__ short Qs[64][PITCH];
    __shared__ short Ks[64][PITCH];
    __shared__ short Vt[64][PITCH];
    __shared__ short Ps[4][16][PITCH];
    __shared__ int sq_s[64];

    const int tid = threadIdx.x;
    const int w = tid >> 6;
    const int lane = tid & 63;
    const int quad = lane >> 4;
    const int l15 = lane & 15;

#pragma unroll
    for (int j = 0; j < 2; ++j) {
        int g = tid + j * 256;
        int kk = g >> 3;
        int c0 = (g & 7) * 8;
        *(uint4*)&Qs[kk][c0] = *(const uint4*)(qt + base + (size_t)(q0 + kk) * DHh + c0);
    }
    if (tid < 64) sq_s[tid] = sid[q0 + tid];
    const int qmin = sid[q0];
    const int qmax = sid[q0 + 63];

    float m_r[4], l_r[4];
    f32x4 O[4];
#pragma unroll
    for (int r = 0; r < 4; ++r) { m_r[r] = -1e30f; l_r[r] = 0.f; O[r] = f32x4{0.f, 0.f, 0.f, 0.f}; }

    for (int k0 = 0; k0 < Ls; k0 += 64) {
        const int kmin = sid[k0];
        const int kmax = sid[k0 + 63];
        if (kmin > qmax) break;
        if (kmax < qmin) continue;

        __syncthreads();
#pragma unroll
        for (int j = 0; j < 2; ++j) {
            int g = tid + j * 256;
            int kk = g >> 3;
            int c0 = (g & 7) * 8;
            *(uint4*)&Ks[kk][c0] = *(const uint4*)(kt + base + (size_t)(k0 + kk) * DHh + c0);
        }
#pragma unroll
        for (int j = 0; j < 2; ++j) {
            int dh0 = (tid >> 6) * 16 + j * 8;
            int kk = tid & 63;
            uint4 vv = *(const uint4*)(vt + base + (size_t)(k0 + kk) * DHh + dh0);
            const unsigned short* pv = (const unsigned short*)&vv;
#pragma unroll
            for (int i = 0; i < 8; ++i) Vt[dh0 + i][kk] = (short)pv[i];
        }
        __syncthreads();

        const int qrow = w * 16 + l15;
        bf16x8 a0 = *(const bf16x8*)&Qs[qrow][quad * 8];
        bf16x8 a1 = *(const bf16x8*)&Qs[qrow][32 + quad * 8];
        f32x4 s[4];
#pragma unroll
        for (int kg = 0; kg < 4; ++kg) {
            bf16x8 b0 = *(const bf16x8*)&Ks[kg * 16 + l15][quad * 8];
            bf16x8 b1 = *(const bf16x8*)&Ks[kg * 16 + l15][32 + quad * 8];
            f32x4 acc = {0.f, 0.f, 0.f, 0.f};
            acc = __builtin_amdgcn_mfma_f32_16x16x32_bf16(a0, b0, acc, 0, 0, 0);
            acc = __builtin_amdgcn_mfma_f32_16x16x32_bf16(a1, b1, acc, 0, 0, 0);
            s[kg] = acc;
        }
        int sqv[4];
#pragma unroll
        for (int r = 0; r < 4; ++r) sqv[r] = sq_s[w * 16 + quad * 4 + r];
#pragma unroll
        for (int kg = 0; kg < 4; ++kg) {
            int skv = sid[k0 + kg * 16 + l15];
#pragma unroll
            for (int r = 0; r < 4; ++r) {
                float v = s[kg][r] * (ATTN_SCALE * LOG2E);
                s[kg][r] = (sqv[r] != skv) ? -3.0e38f : v;
            }
        }
        float tmax[4], tsum[4];
#pragma unroll
        for (int r = 0; r < 4; ++r)
            tmax[r] = fmaxf(fmaxf(s[0][r], s[1][r]), fmaxf(s[2][r], s[3][r]));
#pragma unroll
        for (int off = 1; off < 16; off <<= 1)
#pragma unroll
            for (int r = 0; r < 4; ++r)
                tmax[r] = fmaxf(tmax[r], __shfl_xor(tmax[r], off, 64));
        float alpha[4];
#pragma unroll
        for (int r = 0; r < 4; ++r) {
            float mn = fmaxf(m_r[r], tmax[r]);
            alpha[r] = exp2f(m_r[r] - mn);
            m_r[r] = mn;
        }
#pragma unroll
        for (int kg = 0; kg < 4; ++kg)
#pragma unroll
            for (int r = 0; r < 4; ++r)
                s[kg][r] = exp2f(s[kg][r] - m_r[r]);
#pragma unroll
        for (int r = 0; r < 4; ++r)
            tsum[r] = s[0][r] + s[1][r] + s[2][r] + s[3][r];
#pragma unroll
        for (int off = 1; off < 16; off <<= 1)
#pragma unroll
            for (int r = 0; r < 4; ++r)
                tsum[r] += __shfl_xor(tsum[r], off, 64);
#pragma unroll
        for (int r = 0; r < 4; ++r) {
            l_r[r] = l_r[r] * alpha[r] + tsum[r];
            O[0][r] *= alpha[r]; O[1][r] *= alpha[r]; O[2][r] *= alpha[r]; O[3][r] *= alpha[r];
        }
#pragma unroll
        for (int kg = 0; kg < 4; ++kg)
#pragma unroll
            for (int r = 0; r < 4; ++r)
                Ps[w][quad * 4 + r][kg * 16 + l15] = (short)f2bf(s[kg][r]);
        bf16x8 pa0 = *(const bf16x8*)&Ps[w][l15][quad * 8];
        bf16x8 pa1 = *(const bf16x8*)&Ps[w][l15][32 + quad * 8];
#pragma unroll
        for (int ng = 0; ng < 4; ++ng) {
            bf16x8 vb0 = *(const bf16x8*)&Vt[ng * 16 + l15][quad * 8];
            bf16x8 vb1 = *(const bf16x8*)&Vt[ng * 16 + l15][32 + quad * 8];
            O[ng] = __builtin_amdgcn_mfma_f32_16x16x32_bf16(pa0, vb0, O[ng], 0, 0, 0);
            O[ng] = __builtin_amdgcn_mfma_f32_16x16x32_bf16(pa1, vb1, O[ng], 0, 0, 0);
        }
    }

    float inv_l[4];
#pragma unroll
    for (int r = 0; r < 4; ++r) inv_l[r] = 1.0f / l_r[r];
#pragma unroll
    for (int ng = 0; ng < 4; ++ng)
#pragma unroll
        for (int r = 0; r < 4; ++r) {
            int q = q0 + w * 16 + quad * 4 + r;
            ctxb[((size_t)b * Ls + q) * Dd + h * DHh + ng * 16 + l15] = f2bf(O[ng][r] * inv_l[r]);
        }
}

// ---------------- launcher ----------------
extern "C" void kernel_launch(void* const* d_in, const int* in_sizes, int n_in,
                              void* d_out, int out_size, void* d_ws, size_t ws_size,
                              hipStream_t stream) {
    const float* x = (const float*)d_in[0];
    const int* seq_id = (const int*)d_in[1];
    const float* ln_w = (const float*)d_in[2];
    const float* ln_b = (const float*)d_in[3];
    const float* w_qkv = (const float*)d_in[4];
    const float* q_lora_a = (const float*)d_in[5];
    const float* q_lora_b = (const float*)d_in[6];
    const float* v_lora_a = (const float*)d_in[7];
    const float* v_lora_b = (const float*)d_in[8];
    const float* q_ln_w = (const float*)d_in[9];
    const float* k_ln_w = (const float*)d_in[10];
    const float* w_out = (const float*)d_in[11];
    float* out = (float*)d_out;

    const size_t SZ = (size_t)BL * Dd;        // 4M elements
    float* p = (float*)d_ws;
    float* qkv = p;            p += 3 * SZ;   // fp32 [BL, 3D]
    float* ropec = p;          p += (size_t)Ls * 32;
    float* ropes = p;          p += (size_t)Ls * 32;
    unsigned short* ub = (unsigned short*)p;
    unsigned short* hb = ub;   ub += SZ;      // bf16 [BL, D]
    unsigned short* qt = ub;   ub += SZ;      // bf16 [B,H,L,DH]
    unsigned short* kt = ub;   ub += SZ;
    unsigned short* vt = ub;   ub += SZ;
    unsigned short* ctxb = ub; ub += SZ;      // bf16 [BL, D]
    unsigned short* wqkvb = ub; ub += (size_t)3 * Dd * Dd;
    unsigned short* woutb = ub; ub += (size_t)Dd * Dd;

    rope_table_kernel<<<(Ls * 32) / 256, 256, 0, stream>>>(ropec, ropes);
    cast_bf16_kernel<<<(3 * Dd * Dd) / 1024, 256, 0, stream>>>(w_qkv, wqkvb, 3 * Dd * Dd);
    cast_bf16_kernel<<<(Dd * Dd) / 1024, 256, 0, stream>>>(w_out, woutb, Dd * Dd);
    ln_x_kernel<<<BL, 256, 0, stream>>>(x, ln_w, ln_b, hb);
    {
        dim3 g(3 * Dd / 128, BL / 128);
        gemm_bt_mfma<<<g, 256, 0, stream>>>(hb, wqkvb, qkv, BL, 3 * Dd, Dd);
    }
    qkv_final_kernel<<<BL, 256, 0, stream>>>(hb, qkv, q_lora_a, v_lora_a,
                                             q_lora_b, v_lora_b, q_ln_w, k_ln_w,
                                             ropec, ropes, qt, kt, vt);
    {
        dim3 g(Ls / 64, Hh, Bb);
        attn_kernel<<<g, 256, 0, stream>>>(qt, kt, vt, seq_id, ctxb);
    }
    {
        dim3 g(Dd / 128, BL / 128);
        gemm_bt_mfma<<<g, 256, 0, stream>>>(ctxb, woutb, out, BL, Dd, Dd);
    }
}

// Round 5
// 271.077 us; speedup vs baseline: 11.7432x; 2.1217x over previous
//
#include <hip/hip_runtime.h>
#include <hip/hip_bf16.h>
#include <cmath>

// Problem constants (fixed by reference)
constexpr int Bb = 2;
constexpr int Ls = 2048;
constexpr int Dd = 1024;
constexpr int Hh = 16;
constexpr int DHh = 64;
constexpr int Rr = 32;
constexpr int BL = Bb * Ls;          // 4096
constexpr float LORA_SCALE = 2.0f;   // 64/32
constexpr float LN_EPS = 1e-5f;
constexpr float ATTN_SCALE = 0.125f; // 1/sqrt(64)
constexpr float LOG2E = 1.4426950408889634f;

typedef __attribute__((ext_vector_type(8))) short bf16x8;
typedef __attribute__((ext_vector_type(4))) float f32x4;

__device__ __forceinline__ unsigned short f2bf(float f) {
    __hip_bfloat16 b = __float2bfloat16(f);
    return *reinterpret_cast<unsigned short*>(&b);
}
__device__ __forceinline__ float bf2f(unsigned short u) {
    unsigned int x = ((unsigned int)u) << 16;
    return __uint_as_float(x);
}
__device__ __forceinline__ void async_copy16(const void* g, void* l) {
    __builtin_amdgcn_global_load_lds(
        (__attribute__((address_space(1))) void*)(void*)(size_t)g,
        (__attribute__((address_space(3))) void*)l, 16, 0, 0);
}

// ---------------- block-wide sum over 256 threads ----------------
__device__ __forceinline__ float block_sum_256(float v, float* red) {
#pragma unroll
    for (int o = 32; o > 0; o >>= 1) v += __shfl_down(v, o, 64);
    const int lane = threadIdx.x & 63;
    const int wid = threadIdx.x >> 6;
    if (lane == 0) red[wid] = v;
    __syncthreads();
    float s = red[0] + red[1] + red[2] + red[3];
    __syncthreads();
    return s;
}

// ---------------- 0a. fp32 -> bf16 cast ----------------
__global__ __launch_bounds__(256) void cast_bf16_kernel(const float* __restrict__ src,
                                                        unsigned short* __restrict__ dst,
                                                        int n) {
    int i = (blockIdx.x * 256 + threadIdx.x) * 4;
    if (i < n) {
        float4 v = *(const float4*)(src + i);
        ushort4 o;
        o.x = f2bf(v.x); o.y = f2bf(v.y); o.z = f2bf(v.z); o.w = f2bf(v.w);
        *(ushort4*)(dst + i) = o;
    }
}

// ---------------- 0b. merge LoRA into w_qkv, cast to bf16 ----------------
// w_eff[e][d] = w_qkv[e][d] + 2*sum_r b[e][r]*a[r][d]  (q rows e<D, v rows e>=2D)
__global__ __launch_bounds__(256) void merge_cast_wqkv(const float* __restrict__ w,
                                                       const float* __restrict__ qa,
                                                       const float* __restrict__ qb,
                                                       const float* __restrict__ va,
                                                       const float* __restrict__ vb,
                                                       unsigned short* __restrict__ dst) {
    const int e = blockIdx.x;        // 0..3071
    const int tid = threadIdx.x;
    const int d0 = tid * 4;
    __shared__ float br[Rr];
    const bool isq = (e < Dd);
    const bool isv = (e >= 2 * Dd);
    const float* bsrc = isq ? (qb + (size_t)e * Rr)
                            : (isv ? (vb + (size_t)(e - 2 * Dd) * Rr) : nullptr);
    const float* asrc = isq ? qa : va;
    if (bsrc && tid < Rr) br[tid] = bsrc[tid];
    __syncthreads();
    float acc[4] = {0.f, 0.f, 0.f, 0.f};
    if (bsrc) {
#pragma unroll 8
        for (int r = 0; r < Rr; ++r) {
            float4 av = *(const float4*)(asrc + (size_t)r * Dd + d0);
            acc[0] += br[r] * av.x; acc[1] += br[r] * av.y;
            acc[2] += br[r] * av.z; acc[3] += br[r] * av.w;
        }
    }
    float4 wv = *(const float4*)(w + (size_t)e * Dd + d0);
    ushort4 o;
    o.x = f2bf(wv.x + LORA_SCALE * acc[0]);
    o.y = f2bf(wv.y + LORA_SCALE * acc[1]);
    o.z = f2bf(wv.z + LORA_SCALE * acc[2]);
    o.w = f2bf(wv.w + LORA_SCALE * acc[3]);
    *(ushort4*)(dst + (size_t)e * Dd + d0) = o;
}

// ---------------- 0c. RoPE table: cs/sn[l][f], f in 0..31 ----------------
__global__ __launch_bounds__(256) void rope_table_kernel(float* __restrict__ cs,
                                                         float* __restrict__ sn) {
    int i = blockIdx.x * 256 + threadIdx.x;   // over Ls*32
    int l = i >> 5;
    int f = i & 31;
    float invf = powf(10000.0f, -(float)f * (1.0f / 32.0f));
    float ang = (float)l * invf;
    float s, c;
    sincosf(ang, &s, &c);
    cs[i] = c;
    sn[i] = s;
}

// ---------------- 1. LayerNorm(x) -> h (bf16) ----------------
__global__ __launch_bounds__(256) void ln_x_kernel(const float* __restrict__ x,
                                                   const float* __restrict__ w,
                                                   const float* __restrict__ b,
                                                   unsigned short* __restrict__ hb) {
    const int row = blockIdx.x;
    const int tid = threadIdx.x;
    __shared__ float red[4];
    float4 xv = *(const float4*)(x + (size_t)row * Dd + tid * 4);
    float v[4] = {xv.x, xv.y, xv.z, xv.w};
    float s = v[0] + v[1] + v[2] + v[3];
    float mean = block_sum_256(s, red) * (1.0f / Dd);
    float sq = 0.f;
#pragma unroll
    for (int j = 0; j < 4; ++j) {
        v[j] -= mean;
        sq += v[j] * v[j];
    }
    float var = block_sum_256(sq, red) * (1.0f / Dd);
    float rs = rsqrtf(var + LN_EPS);
    ushort4 o;
    unsigned short* op = (unsigned short*)&o;
#pragma unroll
    for (int j = 0; j < 4; ++j) {
        int d = tid * 4 + j;
        op[j] = f2bf(v[j] * rs * w[d] + b[d]);
    }
    *(ushort4*)(hb + (size_t)row * Dd + tid * 4) = o;
}

// ---------------- 2. MFMA GEMM: C[M,N] = A[M,K] * B[N,K]^T ----------------
__global__ __launch_bounds__(256) void gemm_bt_mfma(const unsigned short* __restrict__ A,
                                                    const unsigned short* __restrict__ B,
                                                    float* __restrict__ C,
                                                    int M, int N, int K) {
    __shared__ short As[128 * 64];
    __shared__ short Bs[128 * 64];
    const int tid = threadIdx.x;
    const int w = tid >> 6, lane = tid & 63, quad = lane >> 4, l15 = lane & 15;
    const int m0 = blockIdx.y * 128, n0 = blockIdx.x * 128;
    const int wm = (w & 1) * 64, wn = (w >> 1) * 64;
    f32x4 acc[4][4];
#pragma unroll
    for (int i = 0; i < 4; ++i)
#pragma unroll
        for (int j = 0; j < 4; ++j) acc[i][j] = f32x4{0.f, 0.f, 0.f, 0.f};

    for (int k0 = 0; k0 < K; k0 += 64) {
#pragma unroll
        for (int j = 0; j < 4; ++j) {
            int c = tid + j * 256;
            int row = c >> 3;
            int jg = (c & 7) ^ (row & 7);
            async_copy16(A + (size_t)(m0 + row) * K + k0 + jg * 8, As + c * 8);
        }
#pragma unroll
        for (int j = 0; j < 4; ++j) {
            int c = tid + j * 256;
            int row = c >> 3;
            int jg = (c & 7) ^ (row & 7);
            async_copy16(B + (size_t)(n0 + row) * K + k0 + jg * 8, Bs + c * 8);
        }
        __syncthreads();
#pragma unroll
        for (int ks = 0; ks < 2; ++ks) {
            bf16x8 a[4], b[4];
#pragma unroll
            for (int mi = 0; mi < 4; ++mi) {
                int row = wm + mi * 16 + l15;
                int ch = (ks * 4 + quad) ^ (row & 7);
                a[mi] = *(const bf16x8*)&As[row * 64 + ch * 8];
            }
#pragma unroll
            for (int ni = 0; ni < 4; ++ni) {
                int row = wn + ni * 16 + l15;
                int ch = (ks * 4 + quad) ^ (row & 7);
                b[ni] = *(const bf16x8*)&Bs[row * 64 + ch * 8];
            }
#pragma unroll
            for (int mi = 0; mi < 4; ++mi)
#pragma unroll
                for (int ni = 0; ni < 4; ++ni)
                    acc[mi][ni] = __builtin_amdgcn_mfma_f32_16x16x32_bf16(a[mi], b[ni], acc[mi][ni], 0, 0, 0);
        }
        __syncthreads();
    }
#pragma unroll
    for (int mi = 0; mi < 4; ++mi)
#pragma unroll
        for (int ni = 0; ni < 4; ++ni)
#pragma unroll
            for (int r = 0; r < 4; ++r)
                C[(size_t)(m0 + wm + mi * 16 + quad * 4 + r) * N + n0 + wn + ni * 16 + l15] =
                    acc[mi][ni][r];
}

// ---------------- 3. Q/K/V finalize (no LoRA — folded into weights) ----------------
// one block per row (256 thr). Reads qkv-row (fp32); emits qt/kt/vt bf16 [B,H,L,DH].
__global__ __launch_bounds__(256) void qkv_final_kernel(const float* __restrict__ qkv,
                                                        const float* __restrict__ qlnw,
                                                        const float* __restrict__ klnw,
                                                        const float* __restrict__ ropec,
                                                        const float* __restrict__ ropes,
                                                        unsigned short* __restrict__ qt,
                                                        unsigned short* __restrict__ kt,
                                                        unsigned short* __restrict__ vt) {
    const int row = blockIdx.x;
    const int b = row >> 11;
    const int l = row & (Ls - 1);
    const int tid = threadIdx.x;
    __shared__ float yrow[Dd];
    __shared__ float red[4];

    const int d0 = tid * 4;
    const int hh = d0 >> 6;
    const int dh0 = d0 & 63;
    float cs4[4], sn4[4];
#pragma unroll
    for (int j = 0; j < 4; ++j) {
        int f = (dh0 + j) & 31;
        cs4[j] = ropec[l * 32 + f];
        sn4[j] = ropes[l * 32 + f];
    }
    const size_t dst_off = (((size_t)(b * Hh + hh)) * Ls + l) * DHh + dh0;

    // ---- Q: LN + RoPE ----
    {
        float4 qv = *(const float4*)(qkv + (size_t)row * (3 * Dd) + d0);
        float v[4] = {qv.x, qv.y, qv.z, qv.w};
        float s = v[0] + v[1] + v[2] + v[3];
        float mean = block_sum_256(s, red) * (1.0f / Dd);
        float sq = 0.f;
#pragma unroll
        for (int j = 0; j < 4; ++j) {
            v[j] -= mean;
            sq += v[j] * v[j];
        }
        float var = block_sum_256(sq, red) * (1.0f / Dd);
        float rs = rsqrtf(var + LN_EPS);
#pragma unroll
        for (int j = 0; j < 4; ++j) yrow[d0 + j] = v[j] * rs * qlnw[d0 + j];
        __syncthreads();
        ushort4 pk;
        unsigned short* pp = (unsigned short*)&pk;
#pragma unroll
        for (int j = 0; j < 4; ++j) {
            int d = d0 + j;
            int dh = dh0 + j;
            float rot = (dh < 32) ? -yrow[d + 32] : yrow[d - 32];
            pp[j] = f2bf(yrow[d] * cs4[j] + rot * sn4[j]);
        }
        *(ushort4*)(qt + dst_off) = pk;
    }
    __syncthreads();  // yrow reuse

    // ---- K: LN + RoPE ----
    {
        float4 kv = *(const float4*)(qkv + (size_t)row * (3 * Dd) + Dd + d0);
        float v[4] = {kv.x, kv.y, kv.z, kv.w};
        float s = v[0] + v[1] + v[2] + v[3];
        float mean = block_sum_256(s, red) * (1.0f / Dd);
        float sq = 0.f;
#pragma unroll
        for (int j = 0; j < 4; ++j) {
            v[j] -= mean;
            sq += v[j] * v[j];
        }
        float var = block_sum_256(sq, red) * (1.0f / Dd);
        float rs = rsqrtf(var + LN_EPS);
#pragma unroll
        for (int j = 0; j < 4; ++j) yrow[d0 + j] = v[j] * rs * klnw[d0 + j];
        __syncthreads();
        ushort4 pk;
        unsigned short* pp = (unsigned short*)&pk;
#pragma unroll
        for (int j = 0; j < 4; ++j) {
            int d = d0 + j;
            int dh = dh0 + j;
            float rot = (dh < 32) ? -yrow[d + 32] : yrow[d - 32];
            pp[j] = f2bf(yrow[d] * cs4[j] + rot * sn4[j]);
        }
        *(ushort4*)(kt + dst_off) = pk;
    }

    // ---- V: straight cast ----
    {
        float4 vv = *(const float4*)(qkv + (size_t)row * (3 * Dd) + 2 * Dd + d0);
        ushort4 pk;
        pk.x = f2bf(vv.x); pk.y = f2bf(vv.y); pk.z = f2bf(vv.z); pk.w = f2bf(vv.w);
        *(ushort4*)(vt + dst_off) = pk;
    }
}

// ---------------- 5. MFMA flash attention ----------------
constexpr int PITCH = 72;  // bf16 elements per LDS row

__global__ __launch_bounds__(256) void attn_kernel(const unsigned short* __restrict__ qt,
                                                   const unsigned short* __restrict__ kt,
                                                   const unsigned short* __restrict__ vt,
                                                   const int* __restrict__ seq_id,
                                                   unsigned short* __restrict__ ctxb) {
    const int q0 = blockIdx.x * 64;
    const int h = blockIdx.y;
    const int b = blockIdx.z;
    const size_t base = ((size_t)(b * Hh + h)) * Ls * DHh;
    const int* sid = seq_id + (size_t)b * Ls;

    __shared__ short Qs[64][PITCH];
    __shared__ short Ks[64][PITCH];
    __shared__ short Vt[64][PITCH];
    __shared__ short Ps[4][16][PITCH];
    __shared__ int sq_s[64];

    const int tid = threadIdx.x;
    const int w = tid >> 6;
    const int lane = tid & 63;
    const int quad = lane >> 4;
    const int l15 = lane & 15;

#pragma unroll
    for (int j = 0; j < 2; ++j) {
        int g = tid + j * 256;
        int kk = g >> 3;
        int c0 = (g & 7) * 8;
        *(uint4*)&Qs[kk][c0] = *(const uint4*)(qt + base + (size_t)(q0 + kk) * DHh + c0);
    }
    if (tid < 64) sq_s[tid] = sid[q0 + tid];
    const int qmin = sid[q0];
    const int qmax = sid[q0 + 63];

    float m_r[4], l_r[4];
    f32x4 O[4];
#pragma unroll
    for (int r = 0; r < 4; ++r) { m_r[r] = -1e30f; l_r[r] = 0.f; O[r] = f32x4{0.f, 0.f, 0.f, 0.f}; }

    for (int k0 = 0; k0 < Ls; k0 += 64) {
        const int kmin = sid[k0];
        const int kmax = sid[k0 + 63];
        if (kmin > qmax) break;
        if (kmax < qmin) continue;

        __syncthreads();
#pragma unroll
        for (int j = 0; j < 2; ++j) {
            int g = tid + j * 256;
            int kk = g >> 3;
            int c0 = (g & 7) * 8;
            *(uint4*)&Ks[kk][c0] = *(const uint4*)(kt + base + (size_t)(k0 + kk) * DHh + c0);
        }
#pragma unroll
        for (int j = 0; j < 2; ++j) {
            int dh0 = (tid >> 6) * 16 + j * 8;
            int kk = tid & 63;
            uint4 vv = *(const uint4*)(vt + base + (size_t)(k0 + kk) * DHh + dh0);
            const unsigned short* pv = (const unsigned short*)&vv;
#pragma unroll
            for (int i = 0; i < 8; ++i) Vt[dh0 + i][kk] = (short)pv[i];
        }
        __syncthreads();

        const int qrow = w * 16 + l15;
        bf16x8 a0 = *(const bf16x8*)&Qs[qrow][quad * 8];
        bf16x8 a1 = *(const bf16x8*)&Qs[qrow][32 + quad * 8];
        f32x4 s[4];
#pragma unroll
        for (int kg = 0; kg < 4; ++kg) {
            bf16x8 b0 = *(const bf16x8*)&Ks[kg * 16 + l15][quad * 8];
            bf16x8 b1 = *(const bf16x8*)&Ks[kg * 16 + l15][32 + quad * 8];
            f32x4 acc = {0.f, 0.f, 0.f, 0.f};
            acc = __builtin_amdgcn_mfma_f32_16x16x32_bf16(a0, b0, acc, 0, 0, 0);
            acc = __builtin_amdgcn_mfma_f32_16x16x32_bf16(a1, b1, acc, 0, 0, 0);
            s[kg] = acc;
        }
        int sqv[4];
#pragma unroll
        for (int r = 0; r < 4; ++r) sqv[r] = sq_s[w * 16 + quad * 4 + r];
#pragma unroll
        for (int kg = 0; kg < 4; ++kg) {
            int skv = sid[k0 + kg * 16 + l15];
#pragma unroll
            for (int r = 0; r < 4; ++r) {
                float v = s[kg][r] * (ATTN_SCALE * LOG2E);
                s[kg][r] = (sqv[r] != skv) ? -3.0e38f : v;
            }
        }
        float tmax[4], tsum[4];
#pragma unroll
        for (int r = 0; r < 4; ++r)
            tmax[r] = fmaxf(fmaxf(s[0][r], s[1][r]), fmaxf(s[2][r], s[3][r]));
#pragma unroll
        for (int off = 1; off < 16; off <<= 1)
#pragma unroll
            for (int r = 0; r < 4; ++r)
                tmax[r] = fmaxf(tmax[r], __shfl_xor(tmax[r], off, 64));
        float alpha[4];
#pragma unroll
        for (int r = 0; r < 4; ++r) {
            float mn = fmaxf(m_r[r], tmax[r]);
            alpha[r] = exp2f(m_r[r] - mn);
            m_r[r] = mn;
        }
#pragma unroll
        for (int kg = 0; kg < 4; ++kg)
#pragma unroll
            for (int r = 0; r < 4; ++r)
                s[kg][r] = exp2f(s[kg][r] - m_r[r]);
#pragma unroll
        for (int r = 0; r < 4; ++r)
            tsum[r] = s[0][r] + s[1][r] + s[2][r] + s[3][r];
#pragma unroll
        for (int off = 1; off < 16; off <<= 1)
#pragma unroll
            for (int r = 0; r < 4; ++r)
                tsum[r] += __shfl_xor(tsum[r], off, 64);
#pragma unroll
        for (int r = 0; r < 4; ++r) {
            l_r[r] = l_r[r] * alpha[r] + tsum[r];
            O[0][r] *= alpha[r]; O[1][r] *= alpha[r]; O[2][r] *= alpha[r]; O[3][r] *= alpha[r];
        }
#pragma unroll
        for (int kg = 0; kg < 4; ++kg)
#pragma unroll
            for (int r = 0; r < 4; ++r)
                Ps[w][quad * 4 + r][kg * 16 + l15] = (short)f2bf(s[kg][r]);
        bf16x8 pa0 = *(const bf16x8*)&Ps[w][l15][quad * 8];
        bf16x8 pa1 = *(const bf16x8*)&Ps[w][l15][32 + quad * 8];
#pragma unroll
        for (int ng = 0; ng < 4; ++ng) {
            bf16x8 vb0 = *(const bf16x8*)&Vt[ng * 16 + l15][quad * 8];
            bf16x8 vb1 = *(const bf16x8*)&Vt[ng * 16 + l15][32 + quad * 8];
            O[ng] = __builtin_amdgcn_mfma_f32_16x16x32_bf16(pa0, vb0, O[ng], 0, 0, 0);
            O[ng] = __builtin_amdgcn_mfma_f32_16x16x32_bf16(pa1, vb1, O[ng], 0, 0, 0);
        }
    }

    float inv_l[4];
#pragma unroll
    for (int r = 0; r < 4; ++r) inv_l[r] = 1.0f / l_r[r];
#pragma unroll
    for (int ng = 0; ng < 4; ++ng)
#pragma unroll
        for (int r = 0; r < 4; ++r) {
            int q = q0 + w * 16 + quad * 4 + r;
            ctxb[((size_t)b * Ls + q) * Dd + h * DHh + ng * 16 + l15] = f2bf(O[ng][r] * inv_l[r]);
        }
}

// ---------------- launcher ----------------
extern "C" void kernel_launch(void* const* d_in, const int* in_sizes, int n_in,
                              void* d_out, int out_size, void* d_ws, size_t ws_size,
                              hipStream_t stream) {
    const float* x = (const float*)d_in[0];
    const int* seq_id = (const int*)d_in[1];
    const float* ln_w = (const float*)d_in[2];
    const float* ln_b = (const float*)d_in[3];
    const float* w_qkv = (const float*)d_in[4];
    const float* q_lora_a = (const float*)d_in[5];
    const float* q_lora_b = (const float*)d_in[6];
    const float* v_lora_a = (const float*)d_in[7];
    const float* v_lora_b = (const float*)d_in[8];
    const float* q_ln_w = (const float*)d_in[9];
    const float* k_ln_w = (const float*)d_in[10];
    const float* w_out = (const float*)d_in[11];
    float* out = (float*)d_out;

    const size_t SZ = (size_t)BL * Dd;        // 4M elements
    float* p = (float*)d_ws;
    float* qkv = p;            p += 3 * SZ;   // fp32 [BL, 3D]
    float* ropec = p;          p += (size_t)Ls * 32;
    float* ropes = p;          p += (size_t)Ls * 32;
    unsigned short* ub = (unsigned short*)p;
    unsigned short* hb = ub;   ub += SZ;      // bf16 [BL, D]
    unsigned short* qt = ub;   ub += SZ;      // bf16 [B,H,L,DH]
    unsigned short* kt = ub;   ub += SZ;
    unsigned short* vt = ub;   ub += SZ;
    unsigned short* ctxb = ub; ub += SZ;      // bf16 [BL, D]
    unsigned short* wqkvb = ub; ub += (size_t)3 * Dd * Dd;
    unsigned short* woutb = ub; ub += (size_t)Dd * Dd;

    rope_table_kernel<<<(Ls * 32) / 256, 256, 0, stream>>>(ropec, ropes);
    merge_cast_wqkv<<<3 * Dd, 256, 0, stream>>>(w_qkv, q_lora_a, q_lora_b,
                                                v_lora_a, v_lora_b, wqkvb);
    cast_bf16_kernel<<<(Dd * Dd) / 1024, 256, 0, stream>>>(w_out, woutb, Dd * Dd);
    ln_x_kernel<<<BL, 256, 0, stream>>>(x, ln_w, ln_b, hb);
    {
        dim3 g(3 * Dd / 128, BL / 128);
        gemm_bt_mfma<<<g, 256, 0, stream>>>(hb, wqkvb, qkv, BL, 3 * Dd, Dd);
    }
    qkv_final_kernel<<<BL, 256, 0, stream>>>(qkv, q_ln_w, k_ln_w,
                                             ropec, ropes, qt, kt, vt);
    {
        dim3 g(Ls / 64, Hh, Bb);
        attn_kernel<<<g, 256, 0, stream>>>(qt, kt, vt, seq_id, ctxb);
    }
    {
        dim3 g(Dd / 128, BL / 128);
        gemm_bt_mfma<<<g, 256, 0, stream>>>(ctxb, woutb, out, BL, Dd, Dd);
    }
}

// Round 6
// 265.810 us; speedup vs baseline: 11.9758x; 1.0198x over previous
//
#include <hip/hip_runtime.h>
#include <hip/hip_bf16.h>
#include <cmath>

// Problem constants (fixed by reference)
constexpr int Bb = 2;
constexpr int Ls = 2048;
constexpr int Dd = 1024;
constexpr int Hh = 16;
constexpr int DHh = 64;
constexpr int Rr = 32;
constexpr int BL = Bb * Ls;          // 4096
constexpr float LORA_SCALE = 2.0f;   // 64/32
constexpr float LN_EPS = 1e-5f;
constexpr float ATTN_SCALE = 0.125f; // 1/sqrt(64)
constexpr float LOG2E = 1.4426950408889634f;

typedef __attribute__((ext_vector_type(8))) short bf16x8;
typedef __attribute__((ext_vector_type(4))) float f32x4;

__device__ __forceinline__ unsigned short f2bf(float f) {
    __hip_bfloat16 b = __float2bfloat16(f);
    return *reinterpret_cast<unsigned short*>(&b);
}
__device__ __forceinline__ float bf2f(unsigned short u) {
    unsigned int x = ((unsigned int)u) << 16;
    return __uint_as_float(x);
}
__device__ __forceinline__ void async_copy16(const void* g, void* l) {
    __builtin_amdgcn_global_load_lds(
        (__attribute__((address_space(1))) void*)(void*)(size_t)g,
        (__attribute__((address_space(3))) void*)l, 16, 0, 0);
}

// ---------------- block-wide sum over 256 threads ----------------
__device__ __forceinline__ float block_sum_256(float v, float* red) {
#pragma unroll
    for (int o = 32; o > 0; o >>= 1) v += __shfl_down(v, o, 64);
    const int lane = threadIdx.x & 63;
    const int wid = threadIdx.x >> 6;
    if (lane == 0) red[wid] = v;
    __syncthreads();
    float s = red[0] + red[1] + red[2] + red[3];
    __syncthreads();
    return s;
}

// ---------------- 0a. fp32 -> bf16 cast ----------------
__global__ __launch_bounds__(256) void cast_bf16_kernel(const float* __restrict__ src,
                                                        unsigned short* __restrict__ dst,
                                                        int n) {
    int i = (blockIdx.x * 256 + threadIdx.x) * 4;
    if (i < n) {
        float4 v = *(const float4*)(src + i);
        ushort4 o;
        o.x = f2bf(v.x); o.y = f2bf(v.y); o.z = f2bf(v.z); o.w = f2bf(v.w);
        *(ushort4*)(dst + i) = o;
    }
}

// ---------------- 0b. merge LoRA into w_qkv, cast to bf16 ----------------
__global__ __launch_bounds__(256) void merge_cast_wqkv(const float* __restrict__ w,
                                                       const float* __restrict__ qa,
                                                       const float* __restrict__ qb,
                                                       const float* __restrict__ va,
                                                       const float* __restrict__ vb,
                                                       unsigned short* __restrict__ dst) {
    const int e = blockIdx.x;        // 0..3071
    const int tid = threadIdx.x;
    const int d0 = tid * 4;
    __shared__ float br[Rr];
    const bool isq = (e < Dd);
    const bool isv = (e >= 2 * Dd);
    const float* bsrc = isq ? (qb + (size_t)e * Rr)
                            : (isv ? (vb + (size_t)(e - 2 * Dd) * Rr) : nullptr);
    const float* asrc = isq ? qa : va;
    if (bsrc && tid < Rr) br[tid] = bsrc[tid];
    __syncthreads();
    float acc[4] = {0.f, 0.f, 0.f, 0.f};
    if (bsrc) {
#pragma unroll 8
        for (int r = 0; r < Rr; ++r) {
            float4 av = *(const float4*)(asrc + (size_t)r * Dd + d0);
            acc[0] += br[r] * av.x; acc[1] += br[r] * av.y;
            acc[2] += br[r] * av.z; acc[3] += br[r] * av.w;
        }
    }
    float4 wv = *(const float4*)(w + (size_t)e * Dd + d0);
    ushort4 o;
    o.x = f2bf(wv.x + LORA_SCALE * acc[0]);
    o.y = f2bf(wv.y + LORA_SCALE * acc[1]);
    o.z = f2bf(wv.z + LORA_SCALE * acc[2]);
    o.w = f2bf(wv.w + LORA_SCALE * acc[3]);
    *(ushort4*)(dst + (size_t)e * Dd + d0) = o;
}

// ---------------- 0c. RoPE table: cs/sn[l][f], f in 0..31 ----------------
__global__ __launch_bounds__(256) void rope_table_kernel(float* __restrict__ cs,
                                                         float* __restrict__ sn) {
    int i = blockIdx.x * 256 + threadIdx.x;   // over Ls*32
    int l = i >> 5;
    int f = i & 31;
    float invf = powf(10000.0f, -(float)f * (1.0f / 32.0f));
    float ang = (float)l * invf;
    float s, c;
    sincosf(ang, &s, &c);
    cs[i] = c;
    sn[i] = s;
}

// ---------------- 1. LayerNorm(x) -> h (bf16) ----------------
__global__ __launch_bounds__(256) void ln_x_kernel(const float* __restrict__ x,
                                                   const float* __restrict__ w,
                                                   const float* __restrict__ b,
                                                   unsigned short* __restrict__ hb) {
    const int row = blockIdx.x;
    const int tid = threadIdx.x;
    __shared__ float red[4];
    float4 xv = *(const float4*)(x + (size_t)row * Dd + tid * 4);
    float v[4] = {xv.x, xv.y, xv.z, xv.w};
    float s = v[0] + v[1] + v[2] + v[3];
    float mean = block_sum_256(s, red) * (1.0f / Dd);
    float sq = 0.f;
#pragma unroll
    for (int j = 0; j < 4; ++j) {
        v[j] -= mean;
        sq += v[j] * v[j];
    }
    float var = block_sum_256(sq, red) * (1.0f / Dd);
    float rs = rsqrtf(var + LN_EPS);
    ushort4 o;
    unsigned short* op = (unsigned short*)&o;
#pragma unroll
    for (int j = 0; j < 4; ++j) {
        int d = tid * 4 + j;
        op[j] = f2bf(v[j] * rs * w[d] + b[d]);
    }
    *(ushort4*)(hb + (size_t)row * Dd + tid * 4) = o;
}

// ---------------- 2. MFMA GEMM: C[M,N] = A[M,K] * B[N,K]^T ----------------
__global__ __launch_bounds__(256) void gemm_bt_mfma(const unsigned short* __restrict__ A,
                                                    const unsigned short* __restrict__ B,
                                                    float* __restrict__ C,
                                                    int M, int N, int K) {
    __shared__ short As[128 * 64];
    __shared__ short Bs[128 * 64];
    const int tid = threadIdx.x;
    const int w = tid >> 6, lane = tid & 63, quad = lane >> 4, l15 = lane & 15;
    const int m0 = blockIdx.y * 128, n0 = blockIdx.x * 128;
    const int wm = (w & 1) * 64, wn = (w >> 1) * 64;
    f32x4 acc[4][4];
#pragma unroll
    for (int i = 0; i < 4; ++i)
#pragma unroll
        for (int j = 0; j < 4; ++j) acc[i][j] = f32x4{0.f, 0.f, 0.f, 0.f};

    for (int k0 = 0; k0 < K; k0 += 64) {
#pragma unroll
        for (int j = 0; j < 4; ++j) {
            int c = tid + j * 256;
            int row = c >> 3;
            int jg = (c & 7) ^ (row & 7);
            async_copy16(A + (size_t)(m0 + row) * K + k0 + jg * 8, As + c * 8);
        }
#pragma unroll
        for (int j = 0; j < 4; ++j) {
            int c = tid + j * 256;
            int row = c >> 3;
            int jg = (c & 7) ^ (row & 7);
            async_copy16(B + (size_t)(n0 + row) * K + k0 + jg * 8, Bs + c * 8);
        }
        __syncthreads();
#pragma unroll
        for (int ks = 0; ks < 2; ++ks) {
            bf16x8 a[4], b[4];
#pragma unroll
            for (int mi = 0; mi < 4; ++mi) {
                int row = wm + mi * 16 + l15;
                int ch = (ks * 4 + quad) ^ (row & 7);
                a[mi] = *(const bf16x8*)&As[row * 64 + ch * 8];
            }
#pragma unroll
            for (int ni = 0; ni < 4; ++ni) {
                int row = wn + ni * 16 + l15;
                int ch = (ks * 4 + quad) ^ (row & 7);
                b[ni] = *(const bf16x8*)&Bs[row * 64 + ch * 8];
            }
#pragma unroll
            for (int mi = 0; mi < 4; ++mi)
#pragma unroll
                for (int ni = 0; ni < 4; ++ni)
                    acc[mi][ni] = __builtin_amdgcn_mfma_f32_16x16x32_bf16(a[mi], b[ni], acc[mi][ni], 0, 0, 0);
        }
        __syncthreads();
    }
#pragma unroll
    for (int mi = 0; mi < 4; ++mi)
#pragma unroll
        for (int ni = 0; ni < 4; ++ni)
#pragma unroll
            for (int r = 0; r < 4; ++r)
                C[(size_t)(m0 + wm + mi * 16 + quad * 4 + r) * N + n0 + wn + ni * 16 + l15] =
                    acc[mi][ni][r];
}

// ---------------- 3. Q/K finalize: LN + RoPE -> bf16 [B,H,L,DH] ----------------
__global__ __launch_bounds__(256) void qkv_final_kernel(const float* __restrict__ qkv,
                                                        const float* __restrict__ qlnw,
                                                        const float* __restrict__ klnw,
                                                        const float* __restrict__ ropec,
                                                        const float* __restrict__ ropes,
                                                        unsigned short* __restrict__ qt,
                                                        unsigned short* __restrict__ kt) {
    const int row = blockIdx.x;
    const int b = row >> 11;
    const int l = row & (Ls - 1);
    const int tid = threadIdx.x;
    __shared__ float yrow[Dd];
    __shared__ float red[4];

    const int d0 = tid * 4;
    const int hh = d0 >> 6;
    const int dh0 = d0 & 63;
    float cs4[4], sn4[4];
#pragma unroll
    for (int j = 0; j < 4; ++j) {
        int f = (dh0 + j) & 31;
        cs4[j] = ropec[l * 32 + f];
        sn4[j] = ropes[l * 32 + f];
    }
    const size_t dst_off = (((size_t)(b * Hh + hh)) * Ls + l) * DHh + dh0;

    // ---- Q: LN + RoPE ----
    {
        float4 qv = *(const float4*)(qkv + (size_t)row * (3 * Dd) + d0);
        float v[4] = {qv.x, qv.y, qv.z, qv.w};
        float s = v[0] + v[1] + v[2] + v[3];
        float mean = block_sum_256(s, red) * (1.0f / Dd);
        float sq = 0.f;
#pragma unroll
        for (int j = 0; j < 4; ++j) {
            v[j] -= mean;
            sq += v[j] * v[j];
        }
        float var = block_sum_256(sq, red) * (1.0f / Dd);
        float rs = rsqrtf(var + LN_EPS);
#pragma unroll
        for (int j = 0; j < 4; ++j) yrow[d0 + j] = v[j] * rs * qlnw[d0 + j];
        __syncthreads();
        ushort4 pk;
        unsigned short* pp = (unsigned short*)&pk;
#pragma unroll
        for (int j = 0; j < 4; ++j) {
            int d = d0 + j;
            int dh = dh0 + j;
            float rot = (dh < 32) ? -yrow[d + 32] : yrow[d - 32];
            pp[j] = f2bf(yrow[d] * cs4[j] + rot * sn4[j]);
        }
        *(ushort4*)(qt + dst_off) = pk;
    }
    __syncthreads();  // yrow reuse

    // ---- K: LN + RoPE ----
    {
        float4 kv = *(const float4*)(qkv + (size_t)row * (3 * Dd) + Dd + d0);
        float v[4] = {kv.x, kv.y, kv.z, kv.w};
        float s = v[0] + v[1] + v[2] + v[3];
        float mean = block_sum_256(s, red) * (1.0f / Dd);
        float sq = 0.f;
#pragma unroll
        for (int j = 0; j < 4; ++j) {
            v[j] -= mean;
            sq += v[j] * v[j];
        }
        float var = block_sum_256(sq, red) * (1.0f / Dd);
        float rs = rsqrtf(var + LN_EPS);
#pragma unroll
        for (int j = 0; j < 4; ++j) yrow[d0 + j] = v[j] * rs * klnw[d0 + j];
        __syncthreads();
        ushort4 pk;
        unsigned short* pp = (unsigned short*)&pk;
#pragma unroll
        for (int j = 0; j < 4; ++j) {
            int d = d0 + j;
            int dh = dh0 + j;
            float rot = (dh < 32) ? -yrow[d + 32] : yrow[d - 32];
            pp[j] = f2bf(yrow[d] * cs4[j] + rot * sn4[j]);
        }
        *(ushort4*)(kt + dst_off) = pk;
    }
}

// ---------------- 4. V transpose: qkv fp32 v-section -> vtt bf16 [B,H,DH,L] ----
__global__ __launch_bounds__(256) void transpose_v_kernel(const float* __restrict__ qkv,
                                                          unsigned short* __restrict__ vtt) {
    const int l0 = blockIdx.x * 64;
    const int h = blockIdx.y;
    const int b = blockIdx.z;
    const int tid = threadIdx.x;
    __shared__ short t[64][72];
    const float* src = qkv + (size_t)b * Ls * (3 * Dd) + 2 * Dd + h * 64;
#pragma unroll
    for (int j = 0; j < 2; ++j) {
        int g = tid + j * 256;
        int row = g >> 3;
        int c0 = (g & 7) * 8;
        float4 v0 = *(const float4*)(src + (size_t)(l0 + row) * (3 * Dd) + c0);
        float4 v1 = *(const float4*)(src + (size_t)(l0 + row) * (3 * Dd) + c0 + 4);
        ushort4 o0, o1;
        o0.x = f2bf(v0.x); o0.y = f2bf(v0.y); o0.z = f2bf(v0.z); o0.w = f2bf(v0.w);
        o1.x = f2bf(v1.x); o1.y = f2bf(v1.y); o1.z = f2bf(v1.z); o1.w = f2bf(v1.w);
        *(ushort4*)&t[row][c0] = o0;
        *(ushort4*)&t[row][c0 + 4] = o1;
    }
    __syncthreads();
    unsigned short* dst = vtt + ((size_t)(b * Hh + h) * DHh) * Ls;
#pragma unroll
    for (int j = 0; j < 2; ++j) {
        int g = tid + j * 256;
        int dh = g >> 3;
        int lc = (g & 7) * 8;
        ushort4 o0, o1;
        unsigned short* p0 = (unsigned short*)&o0;
        unsigned short* p1 = (unsigned short*)&o1;
#pragma unroll
        for (int i = 0; i < 4; ++i) p0[i] = (unsigned short)t[lc + i][dh];
#pragma unroll
        for (int i = 0; i < 4; ++i) p1[i] = (unsigned short)t[lc + 4 + i][dh];
        *(ushort4*)(dst + (size_t)dh * Ls + l0 + lc) = o0;
        *(ushort4*)(dst + (size_t)dh * Ls + l0 + lc + 4) = o1;
    }
}

// ---------------- 5. MFMA flash attention (dbuf prefetch, XCD swizzle) -------
constexpr int PSP = 76;  // Ps pitch (152B rows -> conflict-free 2B writes)

__global__ __launch_bounds__(256) void attn_kernel(const unsigned short* __restrict__ qt,
                                                   const unsigned short* __restrict__ kt,
                                                   const unsigned short* __restrict__ vtt,
                                                   const int* __restrict__ seq_id,
                                                   unsigned short* __restrict__ ctxb) {
    // XCD-swizzled decode: all 32 q-blocks of one (b,h) share id%8
    const int id = blockIdx.x;            // 0..1023
    const int c8 = id & 7;
    const int x = (id >> 3) & 31;
    const int g8 = id >> 8;               // 0..3
    const int v = c8 + 8 * g8;            // h + 16*b
    const int b = v >> 4;
    const int h = v & 15;
    const int q0 = x * 64;

    const size_t base = ((size_t)(b * Hh + h)) * Ls * DHh;
    const size_t base_v = ((size_t)(b * Hh + h)) * DHh * Ls;
    const int* sid = seq_id + (size_t)b * Ls;

    __shared__ short Qs[64 * 64];
    __shared__ short Ks[2][64 * 64];
    __shared__ short Vs[2][64 * 64];
    __shared__ short Ps[4][16 * PSP];
    __shared__ int sq_s[64];

    const int tid = threadIdx.x;
    const int w = tid >> 6;
    const int lane = tid & 63;
    const int quad = lane >> 4;
    const int l15 = lane & 15;

    // stage Q (async, xor-swizzled chunks)
#pragma unroll
    for (int j = 0; j < 2; ++j) {
        int cc = tid + j * 256;
        int row = cc >> 3;
        int jg = (cc & 7) ^ (row & 7);
        async_copy16(qt + base + (size_t)(q0 + row) * DHh + jg * 8, Qs + cc * 8);
    }
    if (tid < 64) sq_s[tid] = sid[q0 + tid];
    const int qmin = sid[q0];
    const int qmax = sid[q0 + 63];

    // contiguous needed-tile range via ballot (tiles 0..31)
    bool need = false;
    if (lane < 32) {
        int kmn = sid[lane * 64];
        int kmx = sid[lane * 64 + 63];
        need = (kmn <= qmax) && (kmx >= qmin);
    }
    unsigned long long bmask = __ballot(need);
    const int t0 = __builtin_ctzll(bmask);
    const int t1 = 64 - __builtin_clzll(bmask);

    auto stage = [&](int t, int buf) {
        int k0 = t * 64;
#pragma unroll
        for (int j = 0; j < 2; ++j) {
            int cc = tid + j * 256;
            int row = cc >> 3;
            int jg = (cc & 7) ^ (row & 7);
            async_copy16(kt + base + (size_t)(k0 + row) * DHh + jg * 8, &Ks[buf][cc * 8]);
            async_copy16(vtt + base_v + (size_t)row * Ls + k0 + jg * 8, &Vs[buf][cc * 8]);
        }
    };

    stage(t0, 0);
    __syncthreads();   // Q + first K/V staged (drains vmcnt)

    float m_r[4], l_r[4];
    f32x4 O[4];
#pragma unroll
    for (int r = 0; r < 4; ++r) { m_r[r] = -1e30f; l_r[r] = 0.f; O[r] = f32x4{0.f, 0.f, 0.f, 0.f}; }

    // Q A-frags (LDS stable across loop)
    const int qrow = w * 16 + l15;
    bf16x8 a0 = *(const bf16x8*)&Qs[qrow * 64 + ((0 + quad) ^ (qrow & 7)) * 8];
    bf16x8 a1 = *(const bf16x8*)&Qs[qrow * 64 + ((4 + quad) ^ (qrow & 7)) * 8];

    int cur = 0;
    for (int t = t0; t < t1; ++t) {
        const int k0 = t * 64;
        if (t + 1 < t1) stage(t + 1, cur ^ 1);   // prefetch next tile

        // ---- S = Q K^T : 16 q rows x 64 keys per wave ----
        f32x4 s[4];
#pragma unroll
        for (int kg = 0; kg < 4; ++kg) {
            int krow = kg * 16 + l15;
            bf16x8 b0 = *(const bf16x8*)&Ks[cur][krow * 64 + ((0 + quad) ^ (krow & 7)) * 8];
            bf16x8 b1 = *(const bf16x8*)&Ks[cur][krow * 64 + ((4 + quad) ^ (krow & 7)) * 8];
            f32x4 acc = {0.f, 0.f, 0.f, 0.f};
            acc = __builtin_amdgcn_mfma_f32_16x16x32_bf16(a0, b0, acc, 0, 0, 0);
            acc = __builtin_amdgcn_mfma_f32_16x16x32_bf16(a1, b1, acc, 0, 0, 0);
            s[kg] = acc;
        }
        // scale to log2 domain + (conditional) mask
        const int kmn = sid[k0];
        const int kmx = sid[k0 + 63];
        const bool nomask = (kmn == kmx) && (qmin == qmax) && (kmn == qmin);
#pragma unroll
        for (int kg = 0; kg < 4; ++kg)
#pragma unroll
            for (int r = 0; r < 4; ++r) s[kg][r] *= (ATTN_SCALE * LOG2E);
        if (!nomask) {
            int sqv[4];
#pragma unroll
            for (int r = 0; r < 4; ++r) sqv[r] = sq_s[w * 16 + quad * 4 + r];
#pragma unroll
            for (int kg = 0; kg < 4; ++kg) {
                int skv = sid[k0 + kg * 16 + l15];
#pragma unroll
                for (int r = 0; r < 4; ++r)
                    if (sqv[r] != skv) s[kg][r] = -3.0e38f;
            }
        }
        // online softmax
        float tmax[4], tsum[4];
#pragma unroll
        for (int r = 0; r < 4; ++r)
            tmax[r] = fmaxf(fmaxf(s[0][r], s[1][r]), fmaxf(s[2][r], s[3][r]));
#pragma unroll
        for (int off = 1; off < 16; off <<= 1)
#pragma unroll
            for (int r = 0; r < 4; ++r)
                tmax[r] = fmaxf(tmax[r], __shfl_xor(tmax[r], off, 64));
        float alpha[4];
#pragma unroll
        for (int r = 0; r < 4; ++r) {
            float mn = fmaxf(m_r[r], tmax[r]);
            alpha[r] = exp2f(m_r[r] - mn);
            m_r[r] = mn;
        }
#pragma unroll
        for (int kg = 0; kg < 4; ++kg)
#pragma unroll
            for (int r = 0; r < 4; ++r)
                s[kg][r] = exp2f(s[kg][r] - m_r[r]);
#pragma unroll
        for (int r = 0; r < 4; ++r)
            tsum[r] = s[0][r] + s[1][r] + s[2][r] + s[3][r];
#pragma unroll
        for (int off = 1; off < 16; off <<= 1)
#pragma unroll
            for (int r = 0; r < 4; ++r)
                tsum[r] += __shfl_xor(tsum[r], off, 64);
#pragma unroll
        for (int r = 0; r < 4; ++r) {
            l_r[r] = l_r[r] * alpha[r] + tsum[r];
            O[0][r] *= alpha[r]; O[1][r] *= alpha[r]; O[2][r] *= alpha[r]; O[3][r] *= alpha[r];
        }
        // P -> per-wave LDS (C-layout -> row-major, pitch 76: conflict-free)
#pragma unroll
        for (int kg = 0; kg < 4; ++kg)
#pragma unroll
            for (int r = 0; r < 4; ++r)
                Ps[w][(quad * 4 + r) * PSP + kg * 16 + l15] = (short)f2bf(s[kg][r]);
        // ---- O += P V ----
        bf16x8 pa0 = *(const bf16x8*)&Ps[w][l15 * PSP + quad * 8];
        bf16x8 pa1 = *(const bf16x8*)&Ps[w][l15 * PSP + 32 + quad * 8];
#pragma unroll
        for (int ng = 0; ng < 4; ++ng) {
            int vrow = ng * 16 + l15;   // dh
            bf16x8 vb0 = *(const bf16x8*)&Vs[cur][vrow * 64 + ((0 + quad) ^ (vrow & 7)) * 8];
            bf16x8 vb1 = *(const bf16x8*)&Vs[cur][vrow * 64 + ((4 + quad) ^ (vrow & 7)) * 8];
            O[ng] = __builtin_amdgcn_mfma_f32_16x16x32_bf16(pa0, vb0, O[ng], 0, 0, 0);
            O[ng] = __builtin_amdgcn_mfma_f32_16x16x32_bf16(pa1, vb1, O[ng], 0, 0, 0);
        }
        __syncthreads();   // readers done with buf[cur]; prefetch into buf[cur^1] drained
        cur ^= 1;
    }

    // epilogue
    float inv_l[4];
#pragma unroll
    for (int r = 0; r < 4; ++r) inv_l[r] = 1.0f / l_r[r];
#pragma unroll
    for (int ng = 0; ng < 4; ++ng)
#pragma unroll
        for (int r = 0; r < 4; ++r) {
            int q = q0 + w * 16 + quad * 4 + r;
            ctxb[((size_t)b * Ls + q) * Dd + h * DHh + ng * 16 + l15] = f2bf(O[ng][r] * inv_l[r]);
        }
}

// ---------------- launcher ----------------
extern "C" void kernel_launch(void* const* d_in, const int* in_sizes, int n_in,
                              void* d_out, int out_size, void* d_ws, size_t ws_size,
                              hipStream_t stream) {
    const float* x = (const float*)d_in[0];
    const int* seq_id = (const int*)d_in[1];
    const float* ln_w = (const float*)d_in[2];
    const float* ln_b = (const float*)d_in[3];
    const float* w_qkv = (const float*)d_in[4];
    const float* q_lora_a = (const float*)d_in[5];
    const float* q_lora_b = (const float*)d_in[6];
    const float* v_lora_a = (const float*)d_in[7];
    const float* v_lora_b = (const float*)d_in[8];
    const float* q_ln_w = (const float*)d_in[9];
    const float* k_ln_w = (const float*)d_in[10];
    const float* w_out = (const float*)d_in[11];
    float* out = (float*)d_out;

    const size_t SZ = (size_t)BL * Dd;        // 4M elements
    float* p = (float*)d_ws;
    float* qkv = p;            p += 3 * SZ;   // fp32 [BL, 3D]
    float* ropec = p;          p += (size_t)Ls * 32;
    float* ropes = p;          p += (size_t)Ls * 32;
    unsigned short* ub = (unsigned short*)p;
    unsigned short* hb = ub;   ub += SZ;      // bf16 [BL, D]
    unsigned short* qt = ub;   ub += SZ;      // bf16 [B,H,L,DH]
    unsigned short* kt = ub;   ub += SZ;
    unsigned short* vtt = ub;  ub += SZ;      // bf16 [B,H,DH,L]
    unsigned short* ctxb = ub; ub += SZ;      // bf16 [BL, D]
    unsigned short* wqkvb = ub; ub += (size_t)3 * Dd * Dd;
    unsigned short* woutb = ub; ub += (size_t)Dd * Dd;

    rope_table_kernel<<<(Ls * 32) / 256, 256, 0, stream>>>(ropec, ropes);
    merge_cast_wqkv<<<3 * Dd, 256, 0, stream>>>(w_qkv, q_lora_a, q_lora_b,
                                                v_lora_a, v_lora_b, wqkvb);
    cast_bf16_kernel<<<(Dd * Dd) / 1024, 256, 0, stream>>>(w_out, woutb, Dd * Dd);
    ln_x_kernel<<<BL, 256, 0, stream>>>(x, ln_w, ln_b, hb);
    {
        dim3 g(3 * Dd / 128, BL / 128);
        gemm_bt_mfma<<<g, 256, 0, stream>>>(hb, wqkvb, qkv, BL, 3 * Dd, Dd);
    }
    qkv_final_kernel<<<BL, 256, 0, stream>>>(qkv, q_ln_w, k_ln_w,
                                             ropec, ropes, qt, kt);
    {
        dim3 g(Ls / 64, Hh, Bb);
        transpose_v_kernel<<<g, 256, 0, stream>>>(qkv, vtt);
    }
    attn_kernel<<<1024, 256, 0, stream>>>(qt, kt, vtt, seq_id, ctxb);
    {
        dim3 g(Dd / 128, BL / 128);
        gemm_bt_mfma<<<g, 256, 0, stream>>>(ctxb, woutb, out, BL, Dd, Dd);
    }
}

// Round 8
// 236.942 us; speedup vs baseline: 13.4349x; 1.1218x over previous
//
#include <hip/hip_runtime.h>
#include <hip/hip_bf16.h>
#include <cmath>

// Problem constants (fixed by reference)
constexpr int Bb = 2;
constexpr int Ls = 2048;
constexpr int Dd = 1024;
constexpr int Hh = 16;
constexpr int DHh = 64;
constexpr int Rr = 32;
constexpr int BL = Bb * Ls;          // 4096
constexpr float LORA_SCALE = 2.0f;   // 64/32
constexpr float LN_EPS = 1e-5f;
constexpr float ATTN_SCALE = 0.125f; // 1/sqrt(64)
constexpr float LOG2E = 1.4426950408889634f;
constexpr float QSCL = ATTN_SCALE * LOG2E;  // folded into qt

typedef __attribute__((ext_vector_type(8))) short bf16x8;
typedef __attribute__((ext_vector_type(4))) float f32x4;

__device__ __forceinline__ unsigned short f2bf(float f) {
    __hip_bfloat16 b = __float2bfloat16(f);
    return *reinterpret_cast<unsigned short*>(&b);
}
__device__ __forceinline__ float bf2f(unsigned short u) {
    unsigned int x = ((unsigned int)u) << 16;
    return __uint_as_float(x);
}
__device__ __forceinline__ void async_copy16(const void* g, void* l) {
    __builtin_amdgcn_global_load_lds(
        (__attribute__((address_space(1))) void*)(void*)(size_t)g,
        (__attribute__((address_space(3))) void*)l, 16, 0, 0);
}

// ---------------- block-wide sum over 256 threads ----------------
__device__ __forceinline__ float block_sum_256(float v, float* red) {
#pragma unroll
    for (int o = 32; o > 0; o >>= 1) v += __shfl_down(v, o, 64);
    const int lane = threadIdx.x & 63;
    const int wid = threadIdx.x >> 6;
    if (lane == 0) red[wid] = v;
    __syncthreads();
    float s = red[0] + red[1] + red[2] + red[3];
    __syncthreads();
    return s;
}

// ---------------- 0a. fp32 -> bf16 cast ----------------
__global__ __launch_bounds__(256) void cast_bf16_kernel(const float* __restrict__ src,
                                                        unsigned short* __restrict__ dst,
                                                        int n) {
    int i = (blockIdx.x * 256 + threadIdx.x) * 4;
    if (i < n) {
        float4 v = *(const float4*)(src + i);
        ushort4 o;
        o.x = f2bf(v.x); o.y = f2bf(v.y); o.z = f2bf(v.z); o.w = f2bf(v.w);
        *(ushort4*)(dst + i) = o;
    }
}

// ---------------- 0b. merge LoRA into w_qkv, cast to bf16 ----------------
__global__ __launch_bounds__(256) void merge_cast_wqkv(const float* __restrict__ w,
                                                       const float* __restrict__ qa,
                                                       const float* __restrict__ qb,
                                                       const float* __restrict__ va,
                                                       const float* __restrict__ vb,
                                                       unsigned short* __restrict__ dst) {
    const int e = blockIdx.x;        // 0..3071
    const int tid = threadIdx.x;
    const int d0 = tid * 4;
    __shared__ float br[Rr];
    const bool isq = (e < Dd);
    const bool isv = (e >= 2 * Dd);
    const float* bsrc = isq ? (qb + (size_t)e * Rr)
                            : (isv ? (vb + (size_t)(e - 2 * Dd) * Rr) : nullptr);
    const float* asrc = isq ? qa : va;
    if (bsrc && tid < Rr) br[tid] = bsrc[tid];
    __syncthreads();
    float acc[4] = {0.f, 0.f, 0.f, 0.f};
    if (bsrc) {
#pragma unroll 8
        for (int r = 0; r < Rr; ++r) {
            float4 av = *(const float4*)(asrc + (size_t)r * Dd + d0);
            acc[0] += br[r] * av.x; acc[1] += br[r] * av.y;
            acc[2] += br[r] * av.z; acc[3] += br[r] * av.w;
        }
    }
    float4 wv = *(const float4*)(w + (size_t)e * Dd + d0);
    ushort4 o;
    o.x = f2bf(wv.x + LORA_SCALE * acc[0]);
    o.y = f2bf(wv.y + LORA_SCALE * acc[1]);
    o.z = f2bf(wv.z + LORA_SCALE * acc[2]);
    o.w = f2bf(wv.w + LORA_SCALE * acc[3]);
    *(ushort4*)(dst + (size_t)e * Dd + d0) = o;
}

// ---------------- 0c. RoPE table: cs/sn[l][f], f in 0..31 ----------------
__global__ __launch_bounds__(256) void rope_table_kernel(float* __restrict__ cs,
                                                         float* __restrict__ sn) {
    int i = blockIdx.x * 256 + threadIdx.x;   // over Ls*32
    int l = i >> 5;
    int f = i & 31;
    float invf = powf(10000.0f, -(float)f * (1.0f / 32.0f));
    float ang = (float)l * invf;
    float s, c;
    sincosf(ang, &s, &c);
    cs[i] = c;
    sn[i] = s;
}

// ---------------- 1. LayerNorm(x) -> h (bf16) ----------------
__global__ __launch_bounds__(256) void ln_x_kernel(const float* __restrict__ x,
                                                   const float* __restrict__ w,
                                                   const float* __restrict__ b,
                                                   unsigned short* __restrict__ hb) {
    const int row = blockIdx.x;
    const int tid = threadIdx.x;
    __shared__ float red[4];
    float4 xv = *(const float4*)(x + (size_t)row * Dd + tid * 4);
    float v[4] = {xv.x, xv.y, xv.z, xv.w};
    float s = v[0] + v[1] + v[2] + v[3];
    float mean = block_sum_256(s, red) * (1.0f / Dd);
    float sq = 0.f;
#pragma unroll
    for (int j = 0; j < 4; ++j) {
        v[j] -= mean;
        sq += v[j] * v[j];
    }
    float var = block_sum_256(sq, red) * (1.0f / Dd);
    float rs = rsqrtf(var + LN_EPS);
    ushort4 o;
    unsigned short* op = (unsigned short*)&o;
#pragma unroll
    for (int j = 0; j < 4; ++j) {
        int d = tid * 4 + j;
        op[j] = f2bf(v[j] * rs * w[d] + b[d]);
    }
    *(ushort4*)(hb + (size_t)row * Dd + tid * 4) = o;
}

// ---------------- 2. MFMA GEMM: C[M,N] = A[M,K] * B[N,K]^T ----------------
__global__ __launch_bounds__(256) void gemm_bt_mfma(const unsigned short* __restrict__ A,
                                                    const unsigned short* __restrict__ B,
                                                    float* __restrict__ C,
                                                    int M, int N, int K) {
    __shared__ short As[128 * 64];
    __shared__ short Bs[128 * 64];
    const int tid = threadIdx.x;
    const int w = tid >> 6, lane = tid & 63, quad = lane >> 4, l15 = lane & 15;
    const int m0 = blockIdx.y * 128, n0 = blockIdx.x * 128;
    const int wm = (w & 1) * 64, wn = (w >> 1) * 64;
    f32x4 acc[4][4];
#pragma unroll
    for (int i = 0; i < 4; ++i)
#pragma unroll
        for (int j = 0; j < 4; ++j) acc[i][j] = f32x4{0.f, 0.f, 0.f, 0.f};

    for (int k0 = 0; k0 < K; k0 += 64) {
#pragma unroll
        for (int j = 0; j < 4; ++j) {
            int c = tid + j * 256;
            int row = c >> 3;
            int jg = (c & 7) ^ (row & 7);
            async_copy16(A + (size_t)(m0 + row) * K + k0 + jg * 8, As + c * 8);
        }
#pragma unroll
        for (int j = 0; j < 4; ++j) {
            int c = tid + j * 256;
            int row = c >> 3;
            int jg = (c & 7) ^ (row & 7);
            async_copy16(B + (size_t)(n0 + row) * K + k0 + jg * 8, Bs + c * 8);
        }
        __syncthreads();
#pragma unroll
        for (int ks = 0; ks < 2; ++ks) {
            bf16x8 a[4], b[4];
#pragma unroll
            for (int mi = 0; mi < 4; ++mi) {
                int row = wm + mi * 16 + l15;
                int ch = (ks * 4 + quad) ^ (row & 7);
                a[mi] = *(const bf16x8*)&As[row * 64 + ch * 8];
            }
#pragma unroll
            for (int ni = 0; ni < 4; ++ni) {
                int row = wn + ni * 16 + l15;
                int ch = (ks * 4 + quad) ^ (row & 7);
                b[ni] = *(const bf16x8*)&Bs[row * 64 + ch * 8];
            }
#pragma unroll
            for (int mi = 0; mi < 4; ++mi)
#pragma unroll
                for (int ni = 0; ni < 4; ++ni)
                    acc[mi][ni] = __builtin_amdgcn_mfma_f32_16x16x32_bf16(a[mi], b[ni], acc[mi][ni], 0, 0, 0);
        }
        __syncthreads();
    }
#pragma unroll
    for (int mi = 0; mi < 4; ++mi)
#pragma unroll
        for (int ni = 0; ni < 4; ++ni)
#pragma unroll
            for (int r = 0; r < 4; ++r)
                C[(size_t)(m0 + wm + mi * 16 + quad * 4 + r) * N + n0 + wn + ni * 16 + l15] =
                    acc[mi][ni][r];
}

// ---------------- 3. Q/K finalize: LN + RoPE -> bf16 [B,H,L,DH] ----------------
// Q additionally prescaled by QSCL so attention can use raw exp2.
__global__ __launch_bounds__(256) void qkv_final_kernel(const float* __restrict__ qkv,
                                                        const float* __restrict__ qlnw,
                                                        const float* __restrict__ klnw,
                                                        const float* __restrict__ ropec,
                                                        const float* __restrict__ ropes,
                                                        unsigned short* __restrict__ qt,
                                                        unsigned short* __restrict__ kt) {
    const int row = blockIdx.x;
    const int b = row >> 11;
    const int l = row & (Ls - 1);
    const int tid = threadIdx.x;
    __shared__ float yrow[Dd];
    __shared__ float red[4];

    const int d0 = tid * 4;
    const int hh = d0 >> 6;
    const int dh0 = d0 & 63;
    float cs4[4], sn4[4];
#pragma unroll
    for (int j = 0; j < 4; ++j) {
        int f = (dh0 + j) & 31;
        cs4[j] = ropec[l * 32 + f];
        sn4[j] = ropes[l * 32 + f];
    }
    const size_t dst_off = (((size_t)(b * Hh + hh)) * Ls + l) * DHh + dh0;

    // ---- Q: LN + RoPE + prescale ----
    {
        float4 qv = *(const float4*)(qkv + (size_t)row * (3 * Dd) + d0);
        float v[4] = {qv.x, qv.y, qv.z, qv.w};
        float s = v[0] + v[1] + v[2] + v[3];
        float mean = block_sum_256(s, red) * (1.0f / Dd);
        float sq = 0.f;
#pragma unroll
        for (int j = 0; j < 4; ++j) {
            v[j] -= mean;
            sq += v[j] * v[j];
        }
        float var = block_sum_256(sq, red) * (1.0f / Dd);
        float rs = rsqrtf(var + LN_EPS);
#pragma unroll
        for (int j = 0; j < 4; ++j) yrow[d0 + j] = v[j] * rs * qlnw[d0 + j];
        __syncthreads();
        ushort4 pk;
        unsigned short* pp = (unsigned short*)&pk;
#pragma unroll
        for (int j = 0; j < 4; ++j) {
            int d = d0 + j;
            int dh = dh0 + j;
            float rot = (dh < 32) ? -yrow[d + 32] : yrow[d - 32];
            pp[j] = f2bf((yrow[d] * cs4[j] + rot * sn4[j]) * QSCL);
        }
        *(ushort4*)(qt + dst_off) = pk;
    }
    __syncthreads();  // yrow reuse

    // ---- K: LN + RoPE ----
    {
        float4 kv = *(const float4*)(qkv + (size_t)row * (3 * Dd) + Dd + d0);
        float v[4] = {kv.x, kv.y, kv.z, kv.w};
        float s = v[0] + v[1] + v[2] + v[3];
        float mean = block_sum_256(s, red) * (1.0f / Dd);
        float sq = 0.f;
#pragma unroll
        for (int j = 0; j < 4; ++j) {
            v[j] -= mean;
            sq += v[j] * v[j];
        }
        float var = block_sum_256(sq, red) * (1.0f / Dd);
        float rs = rsqrtf(var + LN_EPS);
#pragma unroll
        for (int j = 0; j < 4; ++j) yrow[d0 + j] = v[j] * rs * klnw[d0 + j];
        __syncthreads();
        ushort4 pk;
        unsigned short* pp = (unsigned short*)&pk;
#pragma unroll
        for (int j = 0; j < 4; ++j) {
            int d = d0 + j;
            int dh = dh0 + j;
            float rot = (dh < 32) ? -yrow[d + 32] : yrow[d - 32];
            pp[j] = f2bf(yrow[d] * cs4[j] + rot * sn4[j]);
        }
        *(ushort4*)(kt + dst_off) = pk;
    }
}

// ---------------- 4. V transpose: qkv fp32 v-section -> vtt bf16 [B,H,DH,L] ----
__global__ __launch_bounds__(256) void transpose_v_kernel(const float* __restrict__ qkv,
                                                          unsigned short* __restrict__ vtt) {
    const int l0 = blockIdx.x * 64;
    const int h = blockIdx.y;
    const int b = blockIdx.z;
    const int tid = threadIdx.x;
    __shared__ short t[64][72];
    const float* src = qkv + (size_t)b * Ls * (3 * Dd) + 2 * Dd + h * 64;
#pragma unroll
    for (int j = 0; j < 2; ++j) {
        int g = tid + j * 256;
        int row = g >> 3;
        int c0 = (g & 7) * 8;
        float4 v0 = *(const float4*)(src + (size_t)(l0 + row) * (3 * Dd) + c0);
        float4 v1 = *(const float4*)(src + (size_t)(l0 + row) * (3 * Dd) + c0 + 4);
        ushort4 o0, o1;
        o0.x = f2bf(v0.x); o0.y = f2bf(v0.y); o0.z = f2bf(v0.z); o0.w = f2bf(v0.w);
        o1.x = f2bf(v1.x); o1.y = f2bf(v1.y); o1.z = f2bf(v1.z); o1.w = f2bf(v1.w);
        *(ushort4*)&t[row][c0] = o0;
        *(ushort4*)&t[row][c0 + 4] = o1;
    }
    __syncthreads();
    unsigned short* dst = vtt + ((size_t)(b * Hh + h) * DHh) * Ls;
#pragma unroll
    for (int j = 0; j < 2; ++j) {
        int g = tid + j * 256;
        int dh = g >> 3;
        int lc = (g & 7) * 8;
        ushort4 o0, o1;
        unsigned short* p0 = (unsigned short*)&o0;
        unsigned short* p1 = (unsigned short*)&o1;
#pragma unroll
        for (int i = 0; i < 4; ++i) p0[i] = (unsigned short)t[lc + i][dh];
#pragma unroll
        for (int i = 0; i < 4; ++i) p1[i] = (unsigned short)t[lc + 4 + i][dh];
        *(ushort4*)(dst + (size_t)dh * Ls + l0 + lc) = o0;
        *(ushort4*)(dst + (size_t)dh * Ls + l0 + lc + 4) = o1;
    }
}

// ---------------- 5. MFMA flash attention -----------------------------------
// R6-proven skeleton: 256 thr / 4 waves / 64 q-rows / grid 1024 / dbuf prefetch.
// Arithmetic-only deltas: p = exp2(s) directly (Q prescaled), deferred l.
constexpr int PSP = 76;  // Ps pitch

__global__ __launch_bounds__(256) void attn_kernel(const unsigned short* __restrict__ qt,
                                                   const unsigned short* __restrict__ kt,
                                                   const unsigned short* __restrict__ vtt,
                                                   const int* __restrict__ seq_id,
                                                   unsigned short* __restrict__ ctxb) {
    // XCD-swizzled decode: all 32 q-blocks of one (b,h) share id%8
    const int id = blockIdx.x;            // 0..1023
    const int c8 = id & 7;
    const int x = (id >> 3) & 31;
    const int g8 = id >> 8;               // 0..3
    const int v = c8 + 8 * g8;            // h + 16*b
    const int b = v >> 4;
    const int h = v & 15;
    const int q0 = x * 64;

    const size_t base = ((size_t)(b * Hh + h)) * Ls * DHh;
    const size_t base_v = ((size_t)(b * Hh + h)) * DHh * Ls;
    const int* sid = seq_id + (size_t)b * Ls;

    __shared__ short Qs[64 * 64];
    __shared__ short Ks[2][64 * 64];
    __shared__ short Vs[2][64 * 64];
    __shared__ short Ps[4][16 * PSP];
    __shared__ int sq_s[64];

    const int tid = threadIdx.x;
    const int w = tid >> 6;
    const int lane = tid & 63;
    const int quad = lane >> 4;
    const int l15 = lane & 15;

    // stage Q (async, xor-swizzled chunks)
#pragma unroll
    for (int j = 0; j < 2; ++j) {
        int cc = tid + j * 256;
        int row = cc >> 3;
        int jg = (cc & 7) ^ (row & 7);
        async_copy16(qt + base + (size_t)(q0 + row) * DHh + jg * 8, Qs + cc * 8);
    }
    if (tid < 64) sq_s[tid] = sid[q0 + tid];
    const int qmin = sid[q0];
    const int qmax = sid[q0 + 63];

    // contiguous needed-tile range via ballot (tiles 0..31)
    bool need = false;
    if (lane < 32) {
        int kmn = sid[lane * 64];
        int kmx = sid[lane * 64 + 63];
        need = (kmn <= qmax) && (kmx >= qmin);
    }
    unsigned long long bmask = __ballot(need);
    const int t0 = __builtin_ctzll(bmask);
    const int t1 = 64 - __builtin_clzll(bmask);

    auto stage = [&](int t, int buf) {
        int k0 = t * 64;
#pragma unroll
        for (int j = 0; j < 2; ++j) {
            int cc = tid + j * 256;
            int row = cc >> 3;
            int jg = (cc & 7) ^ (row & 7);
            async_copy16(kt + base + (size_t)(k0 + row) * DHh + jg * 8, &Ks[buf][cc * 8]);
            async_copy16(vtt + base_v + (size_t)row * Ls + k0 + jg * 8, &Vs[buf][cc * 8]);
        }
    };

    stage(t0, 0);
    __syncthreads();   // Q + first K/V staged (vmcnt drained before barrier)

    float lsum[4] = {0.f, 0.f, 0.f, 0.f};
    f32x4 O[4];
#pragma unroll
    for (int r = 0; r < 4; ++r) O[r] = f32x4{0.f, 0.f, 0.f, 0.f};

    // Q A-frags (Qs stable across loop — no overlay)
    const int qrow = w * 16 + l15;
    bf16x8 a0 = *(const bf16x8*)&Qs[qrow * 64 + ((0 + quad) ^ (qrow & 7)) * 8];
    bf16x8 a1 = *(const bf16x8*)&Qs[qrow * 64 + ((4 + quad) ^ (qrow & 7)) * 8];

    int cur = 0;
    for (int t = t0; t < t1; ++t) {
        const int k0 = t * 64;
        if (t + 1 < t1) stage(t + 1, cur ^ 1);   // prefetch next tile

        // ---- S = Q K^T : 16 q rows x 64 keys per wave (log2 domain already) ----
        f32x4 s[4];
#pragma unroll
        for (int kg = 0; kg < 4; ++kg) {
            int krow = kg * 16 + l15;
            bf16x8 b0 = *(const bf16x8*)&Ks[cur][krow * 64 + ((0 + quad) ^ (krow & 7)) * 8];
            bf16x8 b1 = *(const bf16x8*)&Ks[cur][krow * 64 + ((4 + quad) ^ (krow & 7)) * 8];
            f32x4 acc = {0.f, 0.f, 0.f, 0.f};
            acc = __builtin_amdgcn_mfma_f32_16x16x32_bf16(a0, b0, acc, 0, 0, 0);
            acc = __builtin_amdgcn_mfma_f32_16x16x32_bf16(a1, b1, acc, 0, 0, 0);
            s[kg] = acc;
        }
        // mask only on boundary tiles
        const int kmn = sid[k0];
        const int kmx = sid[k0 + 63];
        const bool nomask = (kmn == kmx) && (qmin == qmax) && (kmn == qmin);
        if (!nomask) {
            int sqv[4];
#pragma unroll
            for (int r = 0; r < 4; ++r) sqv[r] = sq_s[w * 16 + quad * 4 + r];
#pragma unroll
            for (int kg = 0; kg < 4; ++kg) {
                int skv = sid[k0 + kg * 16 + l15];
#pragma unroll
                for (int r = 0; r < 4; ++r)
                    if (sqv[r] != skv) s[kg][r] = -3.0e38f;
            }
        }
        // p = exp2(s); accumulate per-lane l partials; write P (bf16)
#pragma unroll
        for (int kg = 0; kg < 4; ++kg)
#pragma unroll
            for (int r = 0; r < 4; ++r)
                s[kg][r] = __builtin_amdgcn_exp2f(s[kg][r]);
#pragma unroll
        for (int r = 0; r < 4; ++r)
            lsum[r] += s[0][r] + s[1][r] + s[2][r] + s[3][r];
#pragma unroll
        for (int kg = 0; kg < 4; ++kg)
#pragma unroll
            for (int r = 0; r < 4; ++r)
                Ps[w][(quad * 4 + r) * PSP + kg * 16 + l15] = (short)f2bf(s[kg][r]);
        // ---- O += P V ----
        bf16x8 pa0 = *(const bf16x8*)&Ps[w][l15 * PSP + quad * 8];
        bf16x8 pa1 = *(const bf16x8*)&Ps[w][l15 * PSP + 32 + quad * 8];
#pragma unroll
        for (int ng = 0; ng < 4; ++ng) {
            int vrow = ng * 16 + l15;   // dh
            bf16x8 vb0 = *(const bf16x8*)&Vs[cur][vrow * 64 + ((0 + quad) ^ (vrow & 7)) * 8];
            bf16x8 vb1 = *(const bf16x8*)&Vs[cur][vrow * 64 + ((4 + quad) ^ (vrow & 7)) * 8];
            O[ng] = __builtin_amdgcn_mfma_f32_16x16x32_bf16(pa0, vb0, O[ng], 0, 0, 0);
            O[ng] = __builtin_amdgcn_mfma_f32_16x16x32_bf16(pa1, vb1, O[ng], 0, 0, 0);
        }
        __syncthreads();   // readers done with buf[cur]; prefetch drained
        cur ^= 1;
    }

    // deferred l reduction over the 16 key-lanes, then normalize
#pragma unroll
    for (int off = 1; off < 16; off <<= 1)
#pragma unroll
        for (int r = 0; r < 4; ++r)
            lsum[r] += __shfl_xor(lsum[r], off, 64);
    float inv_l[4];
#pragma unroll
    for (int r = 0; r < 4; ++r) inv_l[r] = 1.0f / lsum[r];
#pragma unroll
    for (int ng = 0; ng < 4; ++ng)
#pragma unroll
        for (int r = 0; r < 4; ++r) {
            int q = q0 + w * 16 + quad * 4 + r;
            ctxb[((size_t)b * Ls + q) * Dd + h * DHh + ng * 16 + l15] = f2bf(O[ng][r] * inv_l[r]);
        }
}

// ---------------- launcher ----------------
extern "C" void kernel_launch(void* const* d_in, const int* in_sizes, int n_in,
                              void* d_out, int out_size, void* d_ws, size_t ws_size,
                              hipStream_t stream) {
    const float* x = (const float*)d_in[0];
    const int* seq_id = (const int*)d_in[1];
    const float* ln_w = (const float*)d_in[2];
    const float* ln_b = (const float*)d_in[3];
    const float* w_qkv = (const float*)d_in[4];
    const float* q_lora_a = (const float*)d_in[5];
    const float* q_lora_b = (const float*)d_in[6];
    const float* v_lora_a = (const float*)d_in[7];
    const float* v_lora_b = (const float*)d_in[8];
    const float* q_ln_w = (const float*)d_in[9];
    const float* k_ln_w = (const float*)d_in[10];
    const float* w_out = (const float*)d_in[11];
    float* out = (float*)d_out;

    const size_t SZ = (size_t)BL * Dd;        // 4M elements
    float* p = (float*)d_ws;
    float* qkv = p;            p += 3 * SZ;   // fp32 [BL, 3D]
    float* ropec = p;          p += (size_t)Ls * 32;
    float* ropes = p;          p += (size_t)Ls * 32;
    unsigned short* ub = (unsigned short*)p;
    unsigned short* hb = ub;   ub += SZ;      // bf16 [BL, D]
    unsigned short* qt = ub;   ub += SZ;      // bf16 [B,H,L,DH] (prescaled)
    unsigned short* kt = ub;   ub += SZ;
    unsigned short* vtt = ub;  ub += SZ;      // bf16 [B,H,DH,L]
    unsigned short* ctxb = ub; ub += SZ;      // bf16 [BL, D]
    unsigned short* wqkvb = ub; ub += (size_t)3 * Dd * Dd;
    unsigned short* woutb = ub; ub += (size_t)Dd * Dd;

    rope_table_kernel<<<(Ls * 32) / 256, 256, 0, stream>>>(ropec, ropes);
    merge_cast_wqkv<<<3 * Dd, 256, 0, stream>>>(w_qkv, q_lora_a, q_lora_b,
                                                v_lora_a, v_lora_b, wqkvb);
    cast_bf16_kernel<<<(Dd * Dd) / 1024, 256, 0, stream>>>(w_out, woutb, Dd * Dd);
    ln_x_kernel<<<BL, 256, 0, stream>>>(x, ln_w, ln_b, hb);
    {
        dim3 g(3 * Dd / 128, BL / 128);
        gemm_bt_mfma<<<g, 256, 0, stream>>>(hb, wqkvb, qkv, BL, 3 * Dd, Dd);
    }
    qkv_final_kernel<<<BL, 256, 0, stream>>>(qkv, q_ln_w, k_ln_w,
                                             ropec, ropes, qt, kt);
    {
        dim3 g(Ls / 64, Hh, Bb);
        transpose_v_kernel<<<g, 256, 0, stream>>>(qkv, vtt);
    }
    attn_kernel<<<1024, 256, 0, stream>>>(qt, kt, vtt, seq_id, ctxb);
    {
        dim3 g(Dd / 128, BL / 128);
        gemm_bt_mfma<<<g, 256, 0, stream>>>(ctxb, woutb, out, BL, Dd, Dd);
    }
}

// Round 9
// 222.986 us; speedup vs baseline: 14.2758x; 1.0626x over previous
//
#include <hip/hip_runtime.h>
#include <hip/hip_bf16.h>
#include <cmath>

// Problem constants (fixed by reference)
constexpr int Bb = 2;
constexpr int Ls = 2048;
constexpr int Dd = 1024;
constexpr int Hh = 16;
constexpr int DHh = 64;
constexpr int Rr = 32;
constexpr int BL = Bb * Ls;          // 4096
constexpr float LORA_SCALE = 2.0f;   // 64/32
constexpr float LN_EPS = 1e-5f;
constexpr float ATTN_SCALE = 0.125f; // 1/sqrt(64)
constexpr float LOG2E = 1.4426950408889634f;
constexpr float QSCL = ATTN_SCALE * LOG2E;  // folded into qt

typedef __attribute__((ext_vector_type(8))) short bf16x8;
typedef __attribute__((ext_vector_type(4))) float f32x4;

__device__ __forceinline__ unsigned short f2bf(float f) {
    __hip_bfloat16 b = __float2bfloat16(f);
    return *reinterpret_cast<unsigned short*>(&b);
}
__device__ __forceinline__ float bf2f(unsigned short u) {
    unsigned int x = ((unsigned int)u) << 16;
    return __uint_as_float(x);
}
__device__ __forceinline__ void async_copy16(const void* g, void* l) {
    __builtin_amdgcn_global_load_lds(
        (__attribute__((address_space(1))) void*)(void*)(size_t)g,
        (__attribute__((address_space(3))) void*)l, 16, 0, 0);
}

// ---------------- block-wide sum over 256 threads ----------------
__device__ __forceinline__ float block_sum_256(float v, float* red) {
#pragma unroll
    for (int o = 32; o > 0; o >>= 1) v += __shfl_down(v, o, 64);
    const int lane = threadIdx.x & 63;
    const int wid = threadIdx.x >> 6;
    if (lane == 0) red[wid] = v;
    __syncthreads();
    float s = red[0] + red[1] + red[2] + red[3];
    __syncthreads();
    return s;
}

// ---------------- 0. fused prep: merge-LoRA-wqkv | cast w_out | rope table ----
// grid: [0,3072) merge, [3072,4096) cast w_out, [4096,4352) rope.
__global__ __launch_bounds__(256) void prep_kernel(const float* __restrict__ w,
                                                   const float* __restrict__ qa,
                                                   const float* __restrict__ qb,
                                                   const float* __restrict__ va,
                                                   const float* __restrict__ vb,
                                                   const float* __restrict__ wout,
                                                   unsigned short* __restrict__ wqkvb,
                                                   unsigned short* __restrict__ woutb,
                                                   float* __restrict__ ropec,
                                                   float* __restrict__ ropes) {
    const int blk = blockIdx.x;
    const int tid = threadIdx.x;
    if (blk < 3 * Dd) {
        // ---- merge LoRA into w_qkv row e, cast bf16 ----
        const int e = blk;
        const int d0 = tid * 4;
        __shared__ float br[Rr];
        const bool isq = (e < Dd);
        const bool isv = (e >= 2 * Dd);
        const float* bsrc = isq ? (qb + (size_t)e * Rr)
                                : (isv ? (vb + (size_t)(e - 2 * Dd) * Rr) : nullptr);
        const float* asrc = isq ? qa : va;
        if (bsrc && tid < Rr) br[tid] = bsrc[tid];
        __syncthreads();
        float acc[4] = {0.f, 0.f, 0.f, 0.f};
        if (bsrc) {
#pragma unroll 8
            for (int r = 0; r < Rr; ++r) {
                float4 av = *(const float4*)(asrc + (size_t)r * Dd + d0);
                acc[0] += br[r] * av.x; acc[1] += br[r] * av.y;
                acc[2] += br[r] * av.z; acc[3] += br[r] * av.w;
            }
        }
        float4 wv = *(const float4*)(w + (size_t)e * Dd + d0);
        ushort4 o;
        o.x = f2bf(wv.x + LORA_SCALE * acc[0]);
        o.y = f2bf(wv.y + LORA_SCALE * acc[1]);
        o.z = f2bf(wv.z + LORA_SCALE * acc[2]);
        o.w = f2bf(wv.w + LORA_SCALE * acc[3]);
        *(ushort4*)(wqkvb + (size_t)e * Dd + d0) = o;
    } else if (blk < 4 * Dd) {
        // ---- cast w_out to bf16 ----
        int i = ((blk - 3 * Dd) * 256 + tid) * 4;
        float4 v = *(const float4*)(wout + i);
        ushort4 o;
        o.x = f2bf(v.x); o.y = f2bf(v.y); o.z = f2bf(v.z); o.w = f2bf(v.w);
        *(ushort4*)(woutb + i) = o;
    } else {
        // ---- rope table ----
        int i = (blk - 4 * Dd) * 256 + tid;    // over Ls*32
        int l = i >> 5;
        int f = i & 31;
        float invf = powf(10000.0f, -(float)f * (1.0f / 32.0f));
        float ang = (float)l * invf;
        float s, c;
        sincosf(ang, &s, &c);
        ropec[i] = c;
        ropes[i] = s;
    }
}

// ---------------- 1. LayerNorm(x) -> h (bf16) ----------------
__global__ __launch_bounds__(256) void ln_x_kernel(const float* __restrict__ x,
                                                   const float* __restrict__ w,
                                                   const float* __restrict__ b,
                                                   unsigned short* __restrict__ hb) {
    const int row = blockIdx.x;
    const int tid = threadIdx.x;
    __shared__ float red[4];
    float4 xv = *(const float4*)(x + (size_t)row * Dd + tid * 4);
    float v[4] = {xv.x, xv.y, xv.z, xv.w};
    float s = v[0] + v[1] + v[2] + v[3];
    float mean = block_sum_256(s, red) * (1.0f / Dd);
    float sq = 0.f;
#pragma unroll
    for (int j = 0; j < 4; ++j) {
        v[j] -= mean;
        sq += v[j] * v[j];
    }
    float var = block_sum_256(sq, red) * (1.0f / Dd);
    float rs = rsqrtf(var + LN_EPS);
    ushort4 o;
    unsigned short* op = (unsigned short*)&o;
#pragma unroll
    for (int j = 0; j < 4; ++j) {
        int d = tid * 4 + j;
        op[j] = f2bf(v[j] * rs * w[d] + b[d]);
    }
    *(ushort4*)(hb + (size_t)row * Dd + tid * 4) = o;
}

// ---------------- 2. MFMA GEMM: C[M,N] = A[M,K] * B[N,K]^T ----------------
// OUT_BF16: store bf16 (half the write traffic) else fp32.
template <bool OUT_BF16>
__global__ __launch_bounds__(256) void gemm_bt_mfma(const unsigned short* __restrict__ A,
                                                    const unsigned short* __restrict__ B,
                                                    void* __restrict__ Cv,
                                                    int M, int N, int K) {
    __shared__ short As[128 * 64];
    __shared__ short Bs[128 * 64];
    const int tid = threadIdx.x;
    const int w = tid >> 6, lane = tid & 63, quad = lane >> 4, l15 = lane & 15;
    const int m0 = blockIdx.y * 128, n0 = blockIdx.x * 128;
    const int wm = (w & 1) * 64, wn = (w >> 1) * 64;
    f32x4 acc[4][4];
#pragma unroll
    for (int i = 0; i < 4; ++i)
#pragma unroll
        for (int j = 0; j < 4; ++j) acc[i][j] = f32x4{0.f, 0.f, 0.f, 0.f};

    for (int k0 = 0; k0 < K; k0 += 64) {
#pragma unroll
        for (int j = 0; j < 4; ++j) {
            int c = tid + j * 256;
            int row = c >> 3;
            int jg = (c & 7) ^ (row & 7);
            async_copy16(A + (size_t)(m0 + row) * K + k0 + jg * 8, As + c * 8);
        }
#pragma unroll
        for (int j = 0; j < 4; ++j) {
            int c = tid + j * 256;
            int row = c >> 3;
            int jg = (c & 7) ^ (row & 7);
            async_copy16(B + (size_t)(n0 + row) * K + k0 + jg * 8, Bs + c * 8);
        }
        __syncthreads();
#pragma unroll
        for (int ks = 0; ks < 2; ++ks) {
            bf16x8 a[4], b[4];
#pragma unroll
            for (int mi = 0; mi < 4; ++mi) {
                int row = wm + mi * 16 + l15;
                int ch = (ks * 4 + quad) ^ (row & 7);
                a[mi] = *(const bf16x8*)&As[row * 64 + ch * 8];
            }
#pragma unroll
            for (int ni = 0; ni < 4; ++ni) {
                int row = wn + ni * 16 + l15;
                int ch = (ks * 4 + quad) ^ (row & 7);
                b[ni] = *(const bf16x8*)&Bs[row * 64 + ch * 8];
            }
#pragma unroll
            for (int mi = 0; mi < 4; ++mi)
#pragma unroll
                for (int ni = 0; ni < 4; ++ni)
                    acc[mi][ni] = __builtin_amdgcn_mfma_f32_16x16x32_bf16(a[mi], b[ni], acc[mi][ni], 0, 0, 0);
        }
        __syncthreads();
    }
    if (OUT_BF16) {
        unsigned short* C = (unsigned short*)Cv;
#pragma unroll
        for (int mi = 0; mi < 4; ++mi)
#pragma unroll
            for (int ni = 0; ni < 4; ++ni)
#pragma unroll
                for (int r = 0; r < 4; ++r)
                    C[(size_t)(m0 + wm + mi * 16 + quad * 4 + r) * N + n0 + wn + ni * 16 + l15] =
                        f2bf(acc[mi][ni][r]);
    } else {
        float* C = (float*)Cv;
#pragma unroll
        for (int mi = 0; mi < 4; ++mi)
#pragma unroll
            for (int ni = 0; ni < 4; ++ni)
#pragma unroll
                for (int r = 0; r < 4; ++r)
                    C[(size_t)(m0 + wm + mi * 16 + quad * 4 + r) * N + n0 + wn + ni * 16 + l15] =
                        acc[mi][ni][r];
    }
}

// ---------------- 3. Q/K finalize: LN + RoPE -> bf16 [B,H,L,DH] ----------------
// Input qkv is bf16 now. Q additionally prescaled by QSCL.
__global__ __launch_bounds__(256) void qkv_final_kernel(const unsigned short* __restrict__ qkvb,
                                                        const float* __restrict__ qlnw,
                                                        const float* __restrict__ klnw,
                                                        const float* __restrict__ ropec,
                                                        const float* __restrict__ ropes,
                                                        unsigned short* __restrict__ qt,
                                                        unsigned short* __restrict__ kt) {
    const int row = blockIdx.x;
    const int b = row >> 11;
    const int l = row & (Ls - 1);
    const int tid = threadIdx.x;
    __shared__ float yrow[Dd];
    __shared__ float red[4];

    const int d0 = tid * 4;
    const int hh = d0 >> 6;
    const int dh0 = d0 & 63;
    float cs4[4], sn4[4];
#pragma unroll
    for (int j = 0; j < 4; ++j) {
        int f = (dh0 + j) & 31;
        cs4[j] = ropec[l * 32 + f];
        sn4[j] = ropes[l * 32 + f];
    }
    const size_t dst_off = (((size_t)(b * Hh + hh)) * Ls + l) * DHh + dh0;

    // ---- Q: LN + RoPE + prescale ----
    {
        ushort4 qv = *(const ushort4*)(qkvb + (size_t)row * (3 * Dd) + d0);
        float v[4] = {bf2f(qv.x), bf2f(qv.y), bf2f(qv.z), bf2f(qv.w)};
        float s = v[0] + v[1] + v[2] + v[3];
        float mean = block_sum_256(s, red) * (1.0f / Dd);
        float sq = 0.f;
#pragma unroll
        for (int j = 0; j < 4; ++j) {
            v[j] -= mean;
            sq += v[j] * v[j];
        }
        float var = block_sum_256(sq, red) * (1.0f / Dd);
        float rs = rsqrtf(var + LN_EPS);
#pragma unroll
        for (int j = 0; j < 4; ++j) yrow[d0 + j] = v[j] * rs * qlnw[d0 + j];
        __syncthreads();
        ushort4 pk;
        unsigned short* pp = (unsigned short*)&pk;
#pragma unroll
        for (int j = 0; j < 4; ++j) {
            int d = d0 + j;
            int dh = dh0 + j;
            float rot = (dh < 32) ? -yrow[d + 32] : yrow[d - 32];
            pp[j] = f2bf((yrow[d] * cs4[j] + rot * sn4[j]) * QSCL);
        }
        *(ushort4*)(qt + dst_off) = pk;
    }
    __syncthreads();  // yrow reuse

    // ---- K: LN + RoPE ----
    {
        ushort4 kv = *(const ushort4*)(qkvb + (size_t)row * (3 * Dd) + Dd + d0);
        float v[4] = {bf2f(kv.x), bf2f(kv.y), bf2f(kv.z), bf2f(kv.w)};
        float s = v[0] + v[1] + v[2] + v[3];
        float mean = block_sum_256(s, red) * (1.0f / Dd);
        float sq = 0.f;
#pragma unroll
        for (int j = 0; j < 4; ++j) {
            v[j] -= mean;
            sq += v[j] * v[j];
        }
        float var = block_sum_256(sq, red) * (1.0f / Dd);
        float rs = rsqrtf(var + LN_EPS);
#pragma unroll
        for (int j = 0; j < 4; ++j) yrow[d0 + j] = v[j] * rs * klnw[d0 + j];
        __syncthreads();
        ushort4 pk;
        unsigned short* pp = (unsigned short*)&pk;
#pragma unroll
        for (int j = 0; j < 4; ++j) {
            int d = d0 + j;
            int dh = dh0 + j;
            float rot = (dh < 32) ? -yrow[d + 32] : yrow[d - 32];
            pp[j] = f2bf(yrow[d] * cs4[j] + rot * sn4[j]);
        }
        *(ushort4*)(kt + dst_off) = pk;
    }
}

// ---------------- 4. V transpose: qkv bf16 v-section -> vtt bf16 [B,H,DH,L] ----
__global__ __launch_bounds__(256) void transpose_v_kernel(const unsigned short* __restrict__ qkvb,
                                                          unsigned short* __restrict__ vtt) {
    const int l0 = blockIdx.x * 64;
    const int h = blockIdx.y;
    const int b = blockIdx.z;
    const int tid = threadIdx.x;
    __shared__ short t[64][72];
    const unsigned short* src = qkvb + (size_t)b * Ls * (3 * Dd) + 2 * Dd + h * 64;
#pragma unroll
    for (int j = 0; j < 2; ++j) {
        int g = tid + j * 256;
        int row = g >> 3;
        int c0 = (g & 7) * 8;
        uint4 vv = *(const uint4*)(src + (size_t)(l0 + row) * (3 * Dd) + c0);
        *(uint4*)&t[row][c0] = vv;
    }
    __syncthreads();
    unsigned short* dst = vtt + ((size_t)(b * Hh + h) * DHh) * Ls;
#pragma unroll
    for (int j = 0; j < 2; ++j) {
        int g = tid + j * 256;
        int dh = g >> 3;
        int lc = (g & 7) * 8;
        ushort4 o0, o1;
        unsigned short* p0 = (unsigned short*)&o0;
        unsigned short* p1 = (unsigned short*)&o1;
#pragma unroll
        for (int i = 0; i < 4; ++i) p0[i] = (unsigned short)t[lc + i][dh];
#pragma unroll
        for (int i = 0; i < 4; ++i) p1[i] = (unsigned short)t[lc + 4 + i][dh];
        *(ushort4*)(dst + (size_t)dh * Ls + l0 + lc) = o0;
        *(ushort4*)(dst + (size_t)dh * Ls + l0 + lc + 4) = o1;
    }
}

// ---------------- 5. MFMA flash attention (R8-proven) ------------------------
constexpr int PSP = 76;  // Ps pitch

__global__ __launch_bounds__(256) void attn_kernel(const unsigned short* __restrict__ qt,
                                                   const unsigned short* __restrict__ kt,
                                                   const unsigned short* __restrict__ vtt,
                                                   const int* __restrict__ seq_id,
                                                   unsigned short* __restrict__ ctxb) {
    const int id = blockIdx.x;            // 0..1023
    const int c8 = id & 7;
    const int x = (id >> 3) & 31;
    const int g8 = id >> 8;               // 0..3
    const int v = c8 + 8 * g8;            // h + 16*b
    const int b = v >> 4;
    const int h = v & 15;
    const int q0 = x * 64;

    const size_t base = ((size_t)(b * Hh + h)) * Ls * DHh;
    const size_t base_v = ((size_t)(b * Hh + h)) * DHh * Ls;
    const int* sid = seq_id + (size_t)b * Ls;

    __shared__ short Qs[64 * 64];
    __shared__ short Ks[2][64 * 64];
    __shared__ short Vs[2][64 * 64];
    __shared__ short Ps[4][16 * PSP];
    __shared__ int sq_s[64];

    const int tid = threadIdx.x;
    const int w = tid >> 6;
    const int lane = tid & 63;
    const int quad = lane >> 4;
    const int l15 = lane & 15;

#pragma unroll
    for (int j = 0; j < 2; ++j) {
        int cc = tid + j * 256;
        int row = cc >> 3;
        int jg = (cc & 7) ^ (row & 7);
        async_copy16(qt + base + (size_t)(q0 + row) * DHh + jg * 8, Qs + cc * 8);
    }
    if (tid < 64) sq_s[tid] = sid[q0 + tid];
    const int qmin = sid[q0];
    const int qmax = sid[q0 + 63];

    bool need = false;
    if (lane < 32) {
        int kmn = sid[lane * 64];
        int kmx = sid[lane * 64 + 63];
        need = (kmn <= qmax) && (kmx >= qmin);
    }
    unsigned long long bmask = __ballot(need);
    const int t0 = __builtin_ctzll(bmask);
    const int t1 = 64 - __builtin_clzll(bmask);

    auto stage = [&](int t, int buf) {
        int k0 = t * 64;
#pragma unroll
        for (int j = 0; j < 2; ++j) {
            int cc = tid + j * 256;
            int row = cc >> 3;
            int jg = (cc & 7) ^ (row & 7);
            async_copy16(kt + base + (size_t)(k0 + row) * DHh + jg * 8, &Ks[buf][cc * 8]);
            async_copy16(vtt + base_v + (size_t)row * Ls + k0 + jg * 8, &Vs[buf][cc * 8]);
        }
    };

    stage(t0, 0);
    __syncthreads();

    float lsum[4] = {0.f, 0.f, 0.f, 0.f};
    f32x4 O[4];
#pragma unroll
    for (int r = 0; r < 4; ++r) O[r] = f32x4{0.f, 0.f, 0.f, 0.f};

    const int qrow = w * 16 + l15;
    bf16x8 a0 = *(const bf16x8*)&Qs[qrow * 64 + ((0 + quad) ^ (qrow & 7)) * 8];
    bf16x8 a1 = *(const bf16x8*)&Qs[qrow * 64 + ((4 + quad) ^ (qrow & 7)) * 8];

    int cur = 0;
    for (int t = t0; t < t1; ++t) {
        const int k0 = t * 64;
        if (t + 1 < t1) stage(t + 1, cur ^ 1);

        f32x4 s[4];
#pragma unroll
        for (int kg = 0; kg < 4; ++kg) {
            int krow = kg * 16 + l15;
            bf16x8 b0 = *(const bf16x8*)&Ks[cur][krow * 64 + ((0 + quad) ^ (krow & 7)) * 8];
            bf16x8 b1 = *(const bf16x8*)&Ks[cur][krow * 64 + ((4 + quad) ^ (krow & 7)) * 8];
            f32x4 acc = {0.f, 0.f, 0.f, 0.f};
            acc = __builtin_amdgcn_mfma_f32_16x16x32_bf16(a0, b0, acc, 0, 0, 0);
            acc = __builtin_amdgcn_mfma_f32_16x16x32_bf16(a1, b1, acc, 0, 0, 0);
            s[kg] = acc;
        }
        const int kmn = sid[k0];
        const int kmx = sid[k0 + 63];
        const bool nomask = (kmn == kmx) && (qmin == qmax) && (kmn == qmin);
        if (!nomask) {
            int sqv[4];
#pragma unroll
            for (int r = 0; r < 4; ++r) sqv[r] = sq_s[w * 16 + quad * 4 + r];
#pragma unroll
            for (int kg = 0; kg < 4; ++kg) {
                int skv = sid[k0 + kg * 16 + l15];
#pragma unroll
                for (int r = 0; r < 4; ++r)
                    if (sqv[r] != skv) s[kg][r] = -3.0e38f;
            }
        }
#pragma unroll
        for (int kg = 0; kg < 4; ++kg)
#pragma unroll
            for (int r = 0; r < 4; ++r)
                s[kg][r] = __builtin_amdgcn_exp2f(s[kg][r]);
#pragma unroll
        for (int r = 0; r < 4; ++r)
            lsum[r] += s[0][r] + s[1][r] + s[2][r] + s[3][r];
#pragma unroll
        for (int kg = 0; kg < 4; ++kg)
#pragma unroll
            for (int r = 0; r < 4; ++r)
                Ps[w][(quad * 4 + r) * PSP + kg * 16 + l15] = (short)f2bf(s[kg][r]);
        bf16x8 pa0 = *(const bf16x8*)&Ps[w][l15 * PSP + quad * 8];
        bf16x8 pa1 = *(const bf16x8*)&Ps[w][l15 * PSP + 32 + quad * 8];
#pragma unroll
        for (int ng = 0; ng < 4; ++ng) {
            int vrow = ng * 16 + l15;
            bf16x8 vb0 = *(const bf16x8*)&Vs[cur][vrow * 64 + ((0 + quad) ^ (vrow & 7)) * 8];
            bf16x8 vb1 = *(const bf16x8*)&Vs[cur][vrow * 64 + ((4 + quad) ^ (vrow & 7)) * 8];
            O[ng] = __builtin_amdgcn_mfma_f32_16x16x32_bf16(pa0, vb0, O[ng], 0, 0, 0);
            O[ng] = __builtin_amdgcn_mfma_f32_16x16x32_bf16(pa1, vb1, O[ng], 0, 0, 0);
        }
        __syncthreads();
        cur ^= 1;
    }

#pragma unroll
    for (int off = 1; off < 16; off <<= 1)
#pragma unroll
        for (int r = 0; r < 4; ++r)
            lsum[r] += __shfl_xor(lsum[r], off, 64);
    float inv_l[4];
#pragma unroll
    for (int r = 0; r < 4; ++r) inv_l[r] = 1.0f / lsum[r];
#pragma unroll
    for (int ng = 0; ng < 4; ++ng)
#pragma unroll
        for (int r = 0; r < 4; ++r) {
            int q = q0 + w * 16 + quad * 4 + r;
            ctxb[((size_t)b * Ls + q) * Dd + h * DHh + ng * 16 + l15] = f2bf(O[ng][r] * inv_l[r]);
        }
}

// ---------------- launcher ----------------
extern "C" void kernel_launch(void* const* d_in, const int* in_sizes, int n_in,
                              void* d_out, int out_size, void* d_ws, size_t ws_size,
                              hipStream_t stream) {
    const float* x = (const float*)d_in[0];
    const int* seq_id = (const int*)d_in[1];
    const float* ln_w = (const float*)d_in[2];
    const float* ln_b = (const float*)d_in[3];
    const float* w_qkv = (const float*)d_in[4];
    const float* q_lora_a = (const float*)d_in[5];
    const float* q_lora_b = (const float*)d_in[6];
    const float* v_lora_a = (const float*)d_in[7];
    const float* v_lora_b = (const float*)d_in[8];
    const float* q_ln_w = (const float*)d_in[9];
    const float* k_ln_w = (const float*)d_in[10];
    const float* w_out = (const float*)d_in[11];
    float* out = (float*)d_out;

    const size_t SZ = (size_t)BL * Dd;        // 4M elements
    float* p = (float*)d_ws;
    float* ropec = p;          p += (size_t)Ls * 32;
    float* ropes = p;          p += (size_t)Ls * 32;
    unsigned short* ub = (unsigned short*)p;
    unsigned short* qkvb = ub; ub += 3 * SZ;  // bf16 [BL, 3D]
    unsigned short* hb = ub;   ub += SZ;      // bf16 [BL, D]
    unsigned short* qt = ub;   ub += SZ;      // bf16 [B,H,L,DH] (prescaled)
    unsigned short* kt = ub;   ub += SZ;
    unsigned short* vtt = ub;  ub += SZ;      // bf16 [B,H,DH,L]
    unsigned short* ctxb = ub; ub += SZ;      // bf16 [BL, D]
    unsigned short* wqkvb = ub; ub += (size_t)3 * Dd * Dd;
    unsigned short* woutb = ub; ub += (size_t)Dd * Dd;

    prep_kernel<<<4 * Dd + 256, 256, 0, stream>>>(w_qkv, q_lora_a, q_lora_b,
                                                  v_lora_a, v_lora_b, w_out,
                                                  wqkvb, woutb, ropec, ropes);
    ln_x_kernel<<<BL, 256, 0, stream>>>(x, ln_w, ln_b, hb);
    {
        dim3 g(3 * Dd / 128, BL / 128);
        gemm_bt_mfma<true><<<g, 256, 0, stream>>>(hb, wqkvb, qkvb, BL, 3 * Dd, Dd);
    }
    qkv_final_kernel<<<BL, 256, 0, stream>>>(qkvb, q_ln_w, k_ln_w,
                                             ropec, ropes, qt, kt);
    {
        dim3 g(Ls / 64, Hh, Bb);
        transpose_v_kernel<<<g, 256, 0, stream>>>(qkvb, vtt);
    }
    attn_kernel<<<1024, 256, 0, stream>>>(qt, kt, vtt, seq_id, ctxb);
    {
        dim3 g(Dd / 128, BL / 128);
        gemm_bt_mfma<false><<<g, 256, 0, stream>>>(ctxb, woutb, out, BL, Dd, Dd);
    }
}